// Round 1
// baseline (11228.706 us; speedup 1.0000x reference)
//
#include <hip/hip_runtime.h>
#include <hip/hip_fp16.h>

#define B_    128
#define DIN_  512
#define H_    1024
#define T_    256
#define O_    1024

typedef _Float16 f16;
typedef _Float16 f16x8 __attribute__((ext_vector_type(8)));
typedef float    f32x4 __attribute__((ext_vector_type(4)));

// workspace layout (bytes)
#define OFF_HS    0ull                 // (T_+1)*B_*H_ f16 = 67,371,008  (slot t holds h_t; slot 0 = h0)
#define OFF_C0    67371008ull          // B_*H_ f32
#define OFF_BIASC 67895296ull          // 4096 f32 (rearranged b_ih+b_hh)
#define OFF_VEC0  67911680ull          // 4096 f32 (rearranged x0@W_ih^T + b_ih + b_hh)
#define OFF_WOUT  67928064ull          // O_*H_ f16
#define OFF_ZH    70025216ull          // B_*DIN_ f16
#define OFF_BAR   70156288ull          // 1024 B barrier counters
#define WS_NEED   70157312ull

__device__ __forceinline__ float sigm_f(float x) {
  return 1.f / (1.f + __expf(-x));
}
__device__ __forceinline__ float tanh_f(float x) {
  float ax = fabsf(x);
  float e = __expf(-2.f * ax);
  float t = (1.f - e) / (1.f + e);
  return x < 0.f ? -t : t;
}

// ---------------- K0: misc init (convert z, W_out to fp16; zero barriers) -------------
__global__ void k_misc(const float* __restrict__ z, const float* __restrict__ wout,
                       f16* __restrict__ zh, f16* __restrict__ wouth,
                       unsigned int* __restrict__ bar) {
  int tid = blockIdx.x * blockDim.x + threadIdx.x;
  int nt  = gridDim.x * blockDim.x;
  for (int i = tid; i < B_ * DIN_; i += nt) zh[i] = (f16)z[i];
  for (int i = tid; i < O_ * H_;  i += nt) wouth[i] = (f16)wout[i];
  for (int i = tid; i < 256; i += nt) bar[i] = 0u;
}

// ---------------- K2: bias vectors (rearranged per block layout) ----------------------
// idx = cn*64 + jj*4 + gate, where n = gate*H_ + cn*16 + jj
__global__ void k_bias(const float* __restrict__ Wih, const float* __restrict__ bih,
                       const float* __restrict__ bhh, const float* __restrict__ x0,
                       float* __restrict__ biasc, float* __restrict__ vec0) {
  __shared__ float xs[H_];
  for (int i = threadIdx.x; i < H_; i += blockDim.x) xs[i] = x0[i];
  __syncthreads();
  int n = blockIdx.x * blockDim.x + threadIdx.x;   // 0..4095
  const float* wr = Wih + (size_t)n * H_;
  float s = 0.f;
  for (int k = 0; k < H_; k += 4) {
    float4 w4 = *(const float4*)(wr + k);
    s += w4.x * xs[k] + w4.y * xs[k + 1] + w4.z * xs[k + 2] + w4.w * xs[k + 3];
  }
  float bc = bih[n] + bhh[n];
  int g = n >> 10, hc = n & (H_ - 1);
  int cn = hc >> 4, jj = hc & 15;
  int idx = cn * 64 + jj * 4 + g;
  biasc[idx] = bc;
  vec0[idx]  = s + bc;
}

// ---------------- K1: h0 / c0 via fp16 MFMA ([128,512] x [512,2048]) ------------------
__global__ __launch_bounds__(256) void k_init(
    const f16* __restrict__ zh, const float* __restrict__ Wh, const float* __restrict__ Wc,
    const float* __restrict__ bh, const float* __restrict__ bc,
    f16* __restrict__ hs0, float* __restrict__ c0) {
  __shared__ float red[4 * 128 * 32];   // 64 KB, layout [w][row 128][c 32]
  int tid = threadIdx.x, l = tid & 63, w = tid >> 6;
  int lr = l & 15, lg = l >> 4;
  int n0 = blockIdx.x * 32;             // 64 blocks x 32 cols of 2048
  int ks = w * 128;                     // K-split per wave
  f32x4 acc[8][2];
#pragma unroll
  for (int rt = 0; rt < 8; ++rt)
#pragma unroll
    for (int ct = 0; ct < 2; ++ct) acc[rt][ct] = (f32x4){0.f, 0.f, 0.f, 0.f};

#pragma unroll
  for (int kt = 0; kt < 4; ++kt) {
    int k0 = ks + kt * 32 + lg * 8;
    f16x8 bf[2];
#pragma unroll
    for (int ct = 0; ct < 2; ++ct) {
      int n = n0 + ct * 16 + lr;
      const float* src = (n < H_) ? (Wh + (size_t)n * DIN_) : (Wc + (size_t)(n - H_) * DIN_);
      float4 a4 = *(const float4*)(src + k0);
      float4 b4 = *(const float4*)(src + k0 + 4);
      bf[ct] = (f16x8){(f16)a4.x, (f16)a4.y, (f16)a4.z, (f16)a4.w,
                       (f16)b4.x, (f16)b4.y, (f16)b4.z, (f16)b4.w};
    }
#pragma unroll
    for (int rt = 0; rt < 8; ++rt) {
      f16x8 af = *(const f16x8*)(zh + (size_t)(rt * 16 + lr) * DIN_ + k0);
#pragma unroll
      for (int ct = 0; ct < 2; ++ct)
        acc[rt][ct] = __builtin_amdgcn_mfma_f32_16x16x32_f16(af, bf[ct], acc[rt][ct], 0, 0, 0);
    }
  }
  // partials to LDS (one-time kernel: plain layout, conflicts acceptable)
#pragma unroll
  for (int rt = 0; rt < 8; ++rt)
#pragma unroll
    for (int ct = 0; ct < 2; ++ct) {
      int c = ct * 16 + lr;
#pragma unroll
      for (int reg = 0; reg < 4; ++reg) {
        int rowloc = rt * 16 + lg * 4 + reg;
        red[(w * 128 + rowloc) * 32 + c] = acc[rt][ct][reg];
      }
    }
  __syncthreads();
  for (int i = 0; i < 16; ++i) {
    int e = i * 256 + tid;              // 4096 outputs
    int row = e & 127, c = e >> 7;
    float s = 0.f;
#pragma unroll
    for (int ww = 0; ww < 4; ++ww) s += red[(ww * 128 + row) * 32 + c];
    int n = n0 + c;
    if (n < H_) { s += bh[n]; hs0[(size_t)row * H_ + n] = (f16)s; }
    else        { s += bc[n - H_]; c0[(size_t)row * H_ + (n - H_)] = s; }
  }
}

// ---------------- persistent LSTM kernel ----------------------------------------------
// 256 blocks x 256 thr. 4 groups x 64 blocks; group owns 32 batch rows.
// block: 32 rows x 16 h-cols (64 gate-cols). 4 waves K-split (256 each).
// weights (W_ih+W_hh) as fp16 frags in registers; A direct global->frag; K-reduce via LDS.
__device__ __forceinline__ void load_bf(f16x8 (&bf)[4][8], const float* __restrict__ Wih,
                                        const float* __restrict__ Whh, bool comb,
                                        int hc0, int tid) {
  int l = tid & 63, w = tid >> 6, lr = l & 15, lg = l >> 4;
  int ks = w * 256;
#pragma unroll
  for (int ct = 0; ct < 4; ++ct) {
    int c = ct * 16 + lr;
    int gate = c & 3, jj = c >> 2;
    size_t nrow = (size_t)(gate * H_ + hc0 + jj) * H_;
#pragma unroll
    for (int kt = 0; kt < 8; ++kt) {
      int k0 = ks + kt * 32 + lg * 8;
      float4 h0v = *(const float4*)(Whh + nrow + k0);
      float4 h1v = *(const float4*)(Whh + nrow + k0 + 4);
      if (comb) {
        float4 i0 = *(const float4*)(Wih + nrow + k0);
        float4 i1 = *(const float4*)(Wih + nrow + k0 + 4);
        h0v.x += i0.x; h0v.y += i0.y; h0v.z += i0.z; h0v.w += i0.w;
        h1v.x += i1.x; h1v.y += i1.y; h1v.z += i1.z; h1v.w += i1.w;
      }
      bf[ct][kt] = (f16x8){(f16)h0v.x, (f16)h0v.y, (f16)h0v.z, (f16)h0v.w,
                           (f16)h1v.x, (f16)h1v.y, (f16)h1v.z, (f16)h1v.w};
    }
  }
}

__device__ __forceinline__ void lstm_step(
    int t, f16* __restrict__ hs, const f16x8 (&bf)[4][8],
    const float* __restrict__ bias_s, float* __restrict__ red, float* __restrict__ cst,
    int tid, int rbase, int hc0, unsigned int* __restrict__ ctr) {
  int l = tid & 63, w = tid >> 6, lr = l & 15, lg = l >> 4;
  int ks = w * 256;
  const f16* hsrc = hs + (size_t)t * (B_ * H_);
  f16* hdst = hs + (size_t)(t + 1) * (B_ * H_);

  f16x8 af[2][8];
#pragma unroll
  for (int rt = 0; rt < 2; ++rt)
#pragma unroll
    for (int kt = 0; kt < 8; ++kt)
      af[rt][kt] = *(const f16x8*)(hsrc + (size_t)(rbase + rt * 16 + lr) * H_ +
                                   (ks + kt * 32 + lg * 8));
  f32x4 acc[2][4];
#pragma unroll
  for (int rt = 0; rt < 2; ++rt)
#pragma unroll
    for (int ct = 0; ct < 4; ++ct) acc[rt][ct] = (f32x4){0.f, 0.f, 0.f, 0.f};
#pragma unroll
  for (int kt = 0; kt < 8; ++kt)
#pragma unroll
    for (int rt = 0; rt < 2; ++rt)
#pragma unroll
      for (int ct = 0; ct < 4; ++ct)
        acc[rt][ct] = __builtin_amdgcn_mfma_f32_16x16x32_f16(af[rt][kt], bf[ct][kt],
                                                             acc[rt][ct], 0, 0, 0);
  __syncthreads();                       // red reuse guard
  // partials: layout [w][rowloc 32][c 64], bank-XOR on c bit4 by (rowloc>>2)&1 (= lg&1)
#pragma unroll
  for (int rt = 0; rt < 2; ++rt)
#pragma unroll
    for (int ct = 0; ct < 4; ++ct) {
      int c = (ct * 16 + lr) ^ ((lg & 1) << 4);
#pragma unroll
      for (int reg = 0; reg < 4; ++reg) {
        int rowloc = rt * 16 + lg * 4 + reg;
        red[(w * 32 + rowloc) * 64 + c] = acc[rt][ct][reg];
      }
    }
  __syncthreads();
  // reduce + cell update: 512 elements, 2 per thread
#pragma unroll
  for (int i = 0; i < 2; ++i) {
    int e = i * 256 + tid;
    int row = e >> 4, jj = e & 15;
    int xw = (row >> 2) & 1;
    float g0 = 0.f, g1 = 0.f, g2 = 0.f, g3 = 0.f;
#pragma unroll
    for (int ww = 0; ww < 4; ++ww) {
      f32x4 v = *(const f32x4*)(red + (size_t)((ww * 32 + row) * 64) + ((jj * 4) ^ (xw << 4)));
      g0 += v[0]; g1 += v[1]; g2 += v[2]; g3 += v[3];
    }
    float Gi = g0 + bias_s[jj * 4 + 0];
    float Gf = g1 + bias_s[jj * 4 + 1];
    float Gg = g2 + bias_s[jj * 4 + 2];
    float Go = g3 + bias_s[jj * 4 + 3];
    float ig = sigm_f(Gi), fg = sigm_f(Gf), gg = tanh_f(Gg), og = sigm_f(Go);
    float cold = cst[e];
    float cnew = fg * cold + ig * gg;
    cst[e] = cnew;
    float hnew = og * tanh_f(cnew);
    hdst[(size_t)(rbase + row) * H_ + hc0 + jj] = (f16)hnew;
  }
  // group barrier (generational, monotonic counter)
  __threadfence();
  __syncthreads();
  if (tid == 0) {
    __hip_atomic_fetch_add(ctr, 1u, __ATOMIC_RELEASE, __HIP_MEMORY_SCOPE_AGENT);
    unsigned tgt = 64u * (unsigned)(t + 1);
    int guard = 0;
    while (__hip_atomic_load(ctr, __ATOMIC_ACQUIRE, __HIP_MEMORY_SCOPE_AGENT) < tgt &&
           ++guard < (1 << 20))
      __builtin_amdgcn_s_sleep(1);
  }
  __syncthreads();
  __threadfence();
}

__global__ __launch_bounds__(256, 1) void k_lstm(
    const float* __restrict__ Wih, const float* __restrict__ Whh,
    f16* __restrict__ hs, const float* __restrict__ c0,
    const float* __restrict__ biasc, const float* __restrict__ vec0,
    unsigned int* __restrict__ bar) {
  __shared__ float red[4 * 32 * 64];     // 32 KB
  __shared__ float cst[512];             // 2 KB cell state (32 rows x 16 cols)
  __shared__ float bias0_s[64], biasc_s[64];
  int tid = threadIdx.x;
  int bid = blockIdx.x;
  int grp = bid >> 6, cn = bid & 63;
  int rbase = grp * 32, hc0 = cn * 16;
  unsigned int* ctr = bar + grp * 64;    // 256 B apart
  if (tid < 64) {
    bias0_s[tid] = vec0[cn * 64 + tid];
    biasc_s[tid] = biasc[cn * 64 + tid];
  }
  for (int i = tid; i < 512; i += 256) {
    int row = i >> 4, jj = i & 15;
    cst[i] = c0[(size_t)(rbase + row) * H_ + hc0 + jj];
  }
  __syncthreads();
  f16x8 bf[4][8];                         // 128 VGPRs of weights
  load_bf(bf, Wih, Whh, false, hc0, tid); // step 0: W_hh only
  lstm_step(0, hs, bf, bias0_s, red, cst, tid, rbase, hc0, ctr);
  load_bf(bf, Wih, Whh, true, hc0, tid);  // steps 1..: W_ih + W_hh
  for (int t = 1; t < T_; ++t)
    lstm_step(t, hs, bf, biasc_s, red, cst, tid, rbase, hc0, ctr);
}

// ---------------- projection: out = LeakyReLU(hs[1..256] @ Wout^T + bout) -------------
__global__ __launch_bounds__(256) void k_proj(
    const f16* __restrict__ hs, const f16* __restrict__ wout,
    const float* __restrict__ bout, float* __restrict__ out) {
  __shared__ f16 As[128 * 64];           // 16 KB, rows 128 x 64k, XOR-swizzled
  __shared__ f16 Bs[128 * 64];           // 16 KB
  int tid = threadIdx.x;
  int bid = blockIdx.x;
  int mt = bid >> 3, nt = bid & 7;
  int m0 = mt * 128, n0 = nt * 128;
  int l = tid & 63, w = tid >> 6, lr = l & 15, lg = l >> 4;
  int wr = w >> 1, wc = w & 1;           // 2x2 waves, 64x64 each
  const f16* Aglob = hs + (size_t)B_ * H_;  // slot 1
  f32x4 acc[4][4];
#pragma unroll
  for (int rt = 0; rt < 4; ++rt)
#pragma unroll
    for (int ct = 0; ct < 4; ++ct) acc[rt][ct] = (f32x4){0.f, 0.f, 0.f, 0.f};

  for (int k0 = 0; k0 < H_; k0 += 64) {
    // stage A/B: linear LDS dest, swizzle pre-applied to per-lane global source
#pragma unroll
    for (int rnd = 0; rnd < 4; ++rnd) {
      int s = (rnd * 256 + tid) * 16;    // byte slot
      int rr = s >> 7;
      int kb = (s & 127) ^ ((rr & 7) << 4);
      const char* srcA = (const char*)Aglob + (size_t)(m0 + rr) * (H_ * 2) + k0 * 2 + kb;
      const char* srcB = (const char*)wout  + (size_t)(n0 + rr) * (H_ * 2) + k0 * 2 + kb;
      char* dstA = (char*)As + (size_t)(rnd * 256 + w * 64) * 16;
      char* dstB = (char*)Bs + (size_t)(rnd * 256 + w * 64) * 16;
      __builtin_amdgcn_global_load_lds((const __attribute__((address_space(1))) void*)srcA,
                                       (__attribute__((address_space(3))) void*)dstA, 16, 0, 0);
      __builtin_amdgcn_global_load_lds((const __attribute__((address_space(1))) void*)srcB,
                                       (__attribute__((address_space(3))) void*)dstB, 16, 0, 0);
    }
    __syncthreads();
#pragma unroll
    for (int kk = 0; kk < 2; ++kk) {
      f16x8 bq[4];
#pragma unroll
      for (int ct = 0; ct < 4; ++ct) {
        int coll = wc * 64 + ct * 16 + lr;
        bq[ct] = *(const f16x8*)((const char*)Bs + coll * 128 +
                                 ((kk * 64 + lg * 16) ^ ((coll & 7) << 4)));
      }
#pragma unroll
      for (int rt = 0; rt < 4; ++rt) {
        int rowl = wr * 64 + rt * 16 + lr;
        f16x8 afr = *(const f16x8*)((const char*)As + rowl * 128 +
                                    ((kk * 64 + lg * 16) ^ ((rowl & 7) << 4)));
#pragma unroll
        for (int ct = 0; ct < 4; ++ct)
          acc[rt][ct] = __builtin_amdgcn_mfma_f32_16x16x32_f16(afr, bq[ct], acc[rt][ct], 0, 0, 0);
      }
    }
    __syncthreads();
  }
  // epilogue: bias + LeakyReLU, scatter to [b][t][o]
#pragma unroll
  for (int rt = 0; rt < 4; ++rt)
#pragma unroll
    for (int ct = 0; ct < 4; ++ct) {
      int n = n0 + wc * 64 + ct * 16 + lr;
      float bo = bout[n];
#pragma unroll
      for (int reg = 0; reg < 4; ++reg) {
        int rg = m0 + wr * 64 + rt * 16 + lg * 4 + reg;   // flat row = t*128 + b
        float v = acc[rt][ct][reg] + bo;
        v = v >= 0.f ? v : 0.2f * v;
        out[(size_t)(rg & 127) * (T_ * O_) + (size_t)(rg >> 7) * O_ + n] = v;
      }
    }
}

// ---------------- launch --------------------------------------------------------------
extern "C" void kernel_launch(void* const* d_in, const int* in_sizes, int n_in,
                              void* d_out, int out_size, void* d_ws, size_t ws_size,
                              hipStream_t stream) {
  const float* z    = (const float*)d_in[0];
  const float* Wfch = (const float*)d_in[2];
  const float* bfch = (const float*)d_in[3];
  const float* Wfcc = (const float*)d_in[4];
  const float* bfcc = (const float*)d_in[5];
  const float* Wih  = (const float*)d_in[6];
  const float* bih  = (const float*)d_in[7];
  const float* Whh  = (const float*)d_in[8];
  const float* bhh  = (const float*)d_in[9];
  const float* x0   = (const float*)d_in[10];
  const float* Wout = (const float*)d_in[11];
  const float* bout = (const float*)d_in[12];
  float* out = (float*)d_out;

  if (ws_size < WS_NEED) return;  // will show as absmax failure, not corruption

  char* ws = (char*)d_ws;
  f16* hs      = (f16*)(ws + OFF_HS);
  float* c0    = (float*)(ws + OFF_C0);
  float* biasc = (float*)(ws + OFF_BIASC);
  float* vec0  = (float*)(ws + OFF_VEC0);
  f16* wouth   = (f16*)(ws + OFF_WOUT);
  f16* zh      = (f16*)(ws + OFF_ZH);
  unsigned int* bar = (unsigned int*)(ws + OFF_BAR);

  hipLaunchKernelGGL(k_misc, dim3(256), dim3(256), 0, stream, z, Wout, zh, wouth, bar);
  hipLaunchKernelGGL(k_init, dim3(64), dim3(256), 0, stream, zh, Wfch, Wfcc, bfch, bfcc, hs, c0);
  hipLaunchKernelGGL(k_bias, dim3(16), dim3(256), 0, stream, Wih, bih, bhh, x0, biasc, vec0);
  hipLaunchKernelGGL(k_lstm, dim3(256), dim3(256), 0, stream, Wih, Whh, hs, c0, biasc, vec0, bar);
  hipLaunchKernelGGL(k_proj, dim3(2048), dim3(256), 0, stream, hs, wouth, bout, out);
}

// Round 3
// 2806.455 us; speedup vs baseline: 4.0010x; 4.0010x over previous
//
#include <hip/hip_runtime.h>
#include <hip/hip_fp16.h>

#define B_    128
#define DIN_  512
#define H_    1024
#define T_    256
#define O_    1024

typedef _Float16 f16;
typedef _Float16 f16x8 __attribute__((ext_vector_type(8)));
typedef float    f32x4 __attribute__((ext_vector_type(4)));

// workspace layout (bytes)
#define OFF_HS    0ull                 // (T_+1)*B_*H_ f16 = 67,371,008  (slot t holds h_t; slot 0 = h0)
#define OFF_C0    67371008ull          // B_*H_ f32
#define OFF_BIASC 67895296ull          // 4096 f32 (rearranged b_ih+b_hh)
#define OFF_VEC0  67911680ull          // 4096 f32 (rearranged x0@W_ih^T + b_ih + b_hh)
#define OFF_WOUT  67928064ull          // O_*H_ f16
#define OFF_ZH    70025216ull          // B_*DIN_ f16
#define OFF_BAR   70156288ull          // 1024 B flag words
#define WS_NEED   70157312ull

__device__ __forceinline__ float sigm_f(float x) {
  return 1.f / (1.f + __expf(-x));
}
__device__ __forceinline__ float tanh_f(float x) {
  float ax = fabsf(x);
  float e = __expf(-2.f * ax);
  float t = (1.f - e) / (1.f + e);
  return x < 0.f ? -t : t;
}

// coherent (device-scope, relaxed) 16B h-load as two 8B atomic loads
__device__ __forceinline__ f16x8 ld_h16(const f16* p) {
  union { unsigned long long u[2]; f16x8 v; } r;
  r.u[0] = __hip_atomic_load((const unsigned long long*)p,
                             __ATOMIC_RELAXED, __HIP_MEMORY_SCOPE_AGENT);
  r.u[1] = __hip_atomic_load((const unsigned long long*)p + 1,
                             __ATOMIC_RELAXED, __HIP_MEMORY_SCOPE_AGENT);
  return r.v;
}

// ---------------- K0: misc init (convert z, W_out to fp16; zero flags) ----------------
__global__ void k_misc(const float* __restrict__ z, const float* __restrict__ wout,
                       f16* __restrict__ zh, f16* __restrict__ wouth,
                       unsigned int* __restrict__ bar) {
  int tid = blockIdx.x * blockDim.x + threadIdx.x;
  int nt  = gridDim.x * blockDim.x;
  for (int i = tid; i < B_ * DIN_; i += nt) zh[i] = (f16)z[i];
  for (int i = tid; i < O_ * H_;  i += nt) wouth[i] = (f16)wout[i];
  for (int i = tid; i < 256; i += nt) bar[i] = 0u;
}

// ---------------- K2: bias vectors (rearranged per block layout) ----------------------
// idx = cn*64 + jj*4 + gate, where n = gate*H_ + cn*16 + jj
__global__ void k_bias(const float* __restrict__ Wih, const float* __restrict__ bih,
                       const float* __restrict__ bhh, const float* __restrict__ x0,
                       float* __restrict__ biasc, float* __restrict__ vec0) {
  __shared__ float xs[H_];
  for (int i = threadIdx.x; i < H_; i += blockDim.x) xs[i] = x0[i];
  __syncthreads();
  int n = blockIdx.x * blockDim.x + threadIdx.x;   // 0..4095
  const float* wr = Wih + (size_t)n * H_;
  float s = 0.f;
  for (int k = 0; k < H_; k += 4) {
    float4 w4 = *(const float4*)(wr + k);
    s += w4.x * xs[k] + w4.y * xs[k + 1] + w4.z * xs[k + 2] + w4.w * xs[k + 3];
  }
  float bc = bih[n] + bhh[n];
  int g = n >> 10, hc = n & (H_ - 1);
  int cn = hc >> 4, jj = hc & 15;
  int idx = cn * 64 + jj * 4 + g;
  biasc[idx] = bc;
  vec0[idx]  = s + bc;
}

// ---------------- K1: h0 / c0 via fp16 MFMA ([128,512] x [512,2048]) ------------------
__global__ __launch_bounds__(256) void k_init(
    const f16* __restrict__ zh, const float* __restrict__ Wh, const float* __restrict__ Wc,
    const float* __restrict__ bh, const float* __restrict__ bc,
    f16* __restrict__ hs0, float* __restrict__ c0) {
  __shared__ float red[4 * 128 * 32];   // 64 KB, layout [w][row 128][c 32]
  int tid = threadIdx.x, l = tid & 63, w = tid >> 6;
  int lr = l & 15, lg = l >> 4;
  int n0 = blockIdx.x * 32;             // 64 blocks x 32 cols of 2048
  int ks = w * 128;                     // K-split per wave
  f32x4 acc[8][2];
#pragma unroll
  for (int rt = 0; rt < 8; ++rt)
#pragma unroll
    for (int ct = 0; ct < 2; ++ct) acc[rt][ct] = (f32x4){0.f, 0.f, 0.f, 0.f};

#pragma unroll
  for (int kt = 0; kt < 4; ++kt) {
    int k0 = ks + kt * 32 + lg * 8;
    f16x8 bf[2];
#pragma unroll
    for (int ct = 0; ct < 2; ++ct) {
      int n = n0 + ct * 16 + lr;
      const float* src = (n < H_) ? (Wh + (size_t)n * DIN_) : (Wc + (size_t)(n - H_) * DIN_);
      float4 a4 = *(const float4*)(src + k0);
      float4 b4 = *(const float4*)(src + k0 + 4);
      bf[ct] = (f16x8){(f16)a4.x, (f16)a4.y, (f16)a4.z, (f16)a4.w,
                       (f16)b4.x, (f16)b4.y, (f16)b4.z, (f16)b4.w};
    }
#pragma unroll
    for (int rt = 0; rt < 8; ++rt) {
      f16x8 af = *(const f16x8*)(zh + (size_t)(rt * 16 + lr) * DIN_ + k0);
#pragma unroll
      for (int ct = 0; ct < 2; ++ct)
        acc[rt][ct] = __builtin_amdgcn_mfma_f32_16x16x32_f16(af, bf[ct], acc[rt][ct], 0, 0, 0);
    }
  }
  // partials to LDS (one-time kernel: plain layout, conflicts acceptable)
#pragma unroll
  for (int rt = 0; rt < 8; ++rt)
#pragma unroll
    for (int ct = 0; ct < 2; ++ct) {
      int c = ct * 16 + lr;
#pragma unroll
      for (int reg = 0; reg < 4; ++reg) {
        int rowloc = rt * 16 + lg * 4 + reg;
        red[(w * 128 + rowloc) * 32 + c] = acc[rt][ct][reg];
      }
    }
  __syncthreads();
  for (int i = 0; i < 16; ++i) {
    int e = i * 256 + tid;              // 4096 outputs
    int row = e & 127, c = e >> 7;
    float s = 0.f;
#pragma unroll
    for (int ww = 0; ww < 4; ++ww) s += red[(ww * 128 + row) * 32 + c];
    int n = n0 + c;
    if (n < H_) { s += bh[n]; hs0[(size_t)row * H_ + n] = (f16)s; }
    else        { s += bc[n - H_]; c0[(size_t)row * H_ + (n - H_)] = s; }
  }
}

// ---------------- persistent LSTM kernel ----------------------------------------------
// 256 blocks x 256 thr. 4 groups x 64 blocks; group owns 32 batch rows.
// block: 32 rows x 16 h-cols (64 gate-cols). 4 waves K-split (256 each).
// ALL cross-block transport = relaxed device-scope atomics (compiler emits the
// correct gfx950 coherence bits; no cache-wide wbl2/inv anywhere in the loop).
__device__ __forceinline__ void load_bf(f16x8 (&bf)[4][8], const float* __restrict__ Wih,
                                        const float* __restrict__ Whh, bool comb,
                                        int hc0, int tid) {
  int l = tid & 63, w = tid >> 6, lr = l & 15, lg = l >> 4;
  int ks = w * 256;
#pragma unroll
  for (int ct = 0; ct < 4; ++ct) {
    int c = ct * 16 + lr;
    int gate = c & 3, jj = c >> 2;
    size_t nrow = (size_t)(gate * H_ + hc0 + jj) * H_;
#pragma unroll
    for (int kt = 0; kt < 8; ++kt) {
      int k0 = ks + kt * 32 + lg * 8;
      float4 h0v = *(const float4*)(Whh + nrow + k0);
      float4 h1v = *(const float4*)(Whh + nrow + k0 + 4);
      if (comb) {
        float4 i0 = *(const float4*)(Wih + nrow + k0);
        float4 i1 = *(const float4*)(Wih + nrow + k0 + 4);
        h0v.x += i0.x; h0v.y += i0.y; h0v.z += i0.z; h0v.w += i0.w;
        h1v.x += i1.x; h1v.y += i1.y; h1v.z += i1.z; h1v.w += i1.w;
      }
      bf[ct][kt] = (f16x8){(f16)h0v.x, (f16)h0v.y, (f16)h0v.z, (f16)h0v.w,
                           (f16)h1v.x, (f16)h1v.y, (f16)h1v.z, (f16)h1v.w};
    }
  }
}

__device__ __forceinline__ void lstm_step(
    int t, f16* __restrict__ hs, const f16x8 (&bf)[4][8],
    const float* __restrict__ bias_s, float* __restrict__ red, float* __restrict__ cst,
    f16* __restrict__ hlds,
    int tid, int rbase, int hc0, unsigned int* __restrict__ flags, int cn) {
  int l = tid & 63, w = tid >> 6, lr = l & 15, lg = l >> 4;
  int ks = w * 256;
  const f16* hsrc = hs + (size_t)t * (B_ * H_);
  f16* hdst = hs + (size_t)(t + 1) * (B_ * H_);

  // A-fragments: coherent relaxed-atomic loads (device scope)
  f16x8 af[2][8];
#pragma unroll
  for (int rt = 0; rt < 2; ++rt)
#pragma unroll
    for (int kt = 0; kt < 8; ++kt)
      af[rt][kt] = ld_h16(hsrc + (size_t)(rbase + rt * 16 + lr) * H_ +
                          (ks + kt * 32 + lg * 8));

  f32x4 acc[2][4];
#pragma unroll
  for (int rt = 0; rt < 2; ++rt)
#pragma unroll
    for (int ct = 0; ct < 4; ++ct) acc[rt][ct] = (f32x4){0.f, 0.f, 0.f, 0.f};
#pragma unroll
  for (int kt = 0; kt < 8; ++kt)
#pragma unroll
    for (int rt = 0; rt < 2; ++rt)
#pragma unroll
      for (int ct = 0; ct < 4; ++ct)
        acc[rt][ct] = __builtin_amdgcn_mfma_f32_16x16x32_f16(af[rt][kt], bf[ct][kt],
                                                             acc[rt][ct], 0, 0, 0);
  __syncthreads();                       // red reuse guard
  // partials: layout [w][rowloc 32][c 64], bank-XOR on c bit4 by (rowloc>>2)&1 (= lg&1)
#pragma unroll
  for (int rt = 0; rt < 2; ++rt)
#pragma unroll
    for (int ct = 0; ct < 4; ++ct) {
      int c = (ct * 16 + lr) ^ ((lg & 1) << 4);
#pragma unroll
      for (int reg = 0; reg < 4; ++reg) {
        int rowloc = rt * 16 + lg * 4 + reg;
        red[(w * 32 + rowloc) * 64 + c] = acc[rt][ct][reg];
      }
    }
  __syncthreads();
  // reduce + cell update: 512 elements, 2 per thread; h -> LDS (packed store later)
#pragma unroll
  for (int i = 0; i < 2; ++i) {
    int e = i * 256 + tid;
    int row = e >> 4, jj = e & 15;
    int xw = (row >> 2) & 1;
    float g0 = 0.f, g1 = 0.f, g2 = 0.f, g3 = 0.f;
#pragma unroll
    for (int ww = 0; ww < 4; ++ww) {
      f32x4 v = *(const f32x4*)(red + (size_t)((ww * 32 + row) * 64) + ((jj * 4) ^ (xw << 4)));
      g0 += v[0]; g1 += v[1]; g2 += v[2]; g3 += v[3];
    }
    float Gi = g0 + bias_s[jj * 4 + 0];
    float Gf = g1 + bias_s[jj * 4 + 1];
    float Gg = g2 + bias_s[jj * 4 + 2];
    float Go = g3 + bias_s[jj * 4 + 3];
    float ig = sigm_f(Gi), fg = sigm_f(Gf), gg = tanh_f(Gg), og = sigm_f(Go);
    float cold = cst[e];
    float cnew = fg * cold + ig * gg;
    cst[e] = cnew;
    float hnew = og * tanh_f(cnew);
    hlds[row * 16 + jj] = (f16)hnew;
  }
  __syncthreads();
  // wave 0: coherent h store (128 x 8B), release-drain, flag store, flag poll.
  if (tid < 64) {
    const unsigned long long* q = (const unsigned long long*)hlds;
#pragma unroll
    for (int r2 = 0; r2 < 2; ++r2) {
      int idx = r2 * 64 + tid;           // 0..127
      int row = idx >> 2, qq = idx & 3;
      unsigned long long val = q[row * 4 + qq];
      unsigned long long* dst =
          (unsigned long long*)(hdst + (size_t)(rbase + row) * H_ + hc0) + qq;
      __hip_atomic_store(dst, val, __ATOMIC_RELAXED, __HIP_MEMORY_SCOPE_AGENT);
    }
    asm volatile("s_waitcnt vmcnt(0)" ::: "memory");  // h acked at coherence point
    unsigned tv = (unsigned)(t + 1);
    if (tid == 0)
      __hip_atomic_store(flags + cn, tv, __ATOMIC_RELAXED, __HIP_MEMORY_SCOPE_AGENT);
    // lane i polls block i's flag; bounded guard -> broken sync degrades to
    // wrong answer in <1s, never a watchdog kill.
    int guard = 0;
    while (true) {
      unsigned v = __hip_atomic_load(flags + tid, __ATOMIC_RELAXED,
                                     __HIP_MEMORY_SCOPE_AGENT);
      if (__all(v >= tv)) break;
      if (++guard > (1 << 13)) break;
      __builtin_amdgcn_s_sleep(1);
    }
  }
  __syncthreads();                       // readers start loads only after poll
}

__global__ __launch_bounds__(256, 1) void k_lstm(
    const float* __restrict__ Wih, const float* __restrict__ Whh,
    f16* __restrict__ hs, const float* __restrict__ c0,
    const float* __restrict__ biasc, const float* __restrict__ vec0,
    unsigned int* __restrict__ bar) {
  __shared__ float red[4 * 32 * 64];     // 32 KB
  __shared__ float cst[512];             // 2 KB cell state (32 rows x 16 cols)
  __shared__ f16 hlds[512];              // 1 KB packed h tile
  __shared__ float bias0_s[64], biasc_s[64];
  int tid = threadIdx.x;
  int bid = blockIdx.x;
  int grp = bid >> 6, cn = bid & 63;
  int rbase = grp * 32, hc0 = cn * 16;
  unsigned int* flags = bar + grp * 64;
  if (tid < 64) {
    bias0_s[tid] = vec0[cn * 64 + tid];
    biasc_s[tid] = biasc[cn * 64 + tid];
  }
  for (int i = tid; i < 512; i += 256) {
    int row = i >> 4, jj = i & 15;
    cst[i] = c0[(size_t)(rbase + row) * H_ + hc0 + jj];
  }
  __syncthreads();
  f16x8 bf[4][8];                         // weights in registers
  load_bf(bf, Wih, Whh, false, hc0, tid); // step 0: W_hh only
  lstm_step(0, hs, bf, bias0_s, red, cst, hlds, tid, rbase, hc0, flags, cn);
  load_bf(bf, Wih, Whh, true, hc0, tid);  // steps 1..: W_ih + W_hh
  for (int t = 1; t < T_; ++t)
    lstm_step(t, hs, bf, biasc_s, red, cst, hlds, tid, rbase, hc0, flags, cn);
}

// ---------------- projection: out = LeakyReLU(hs[1..256] @ Wout^T + bout) -------------
__global__ __launch_bounds__(256) void k_proj(
    const f16* __restrict__ hs, const f16* __restrict__ wout,
    const float* __restrict__ bout, float* __restrict__ out) {
  __shared__ f16 As[128 * 64];           // 16 KB, rows 128 x 64k, XOR-swizzled
  __shared__ f16 Bs[128 * 64];           // 16 KB
  int tid = threadIdx.x;
  int bid = blockIdx.x;
  int mt = bid >> 3, nt = bid & 7;
  int m0 = mt * 128, n0 = nt * 128;
  int l = tid & 63, w = tid >> 6, lr = l & 15, lg = l >> 4;
  int wr = w >> 1, wc = w & 1;           // 2x2 waves, 64x64 each
  const f16* Aglob = hs + (size_t)B_ * H_;  // slot 1
  f32x4 acc[4][4];
#pragma unroll
  for (int rt = 0; rt < 4; ++rt)
#pragma unroll
    for (int ct = 0; ct < 4; ++ct) acc[rt][ct] = (f32x4){0.f, 0.f, 0.f, 0.f};

  for (int k0 = 0; k0 < H_; k0 += 64) {
    // stage A/B: linear LDS dest, swizzle pre-applied to per-lane global source
#pragma unroll
    for (int rnd = 0; rnd < 4; ++rnd) {
      int s = (rnd * 256 + tid) * 16;    // byte slot
      int rr = s >> 7;
      int kb = (s & 127) ^ ((rr & 7) << 4);
      const char* srcA = (const char*)Aglob + (size_t)(m0 + rr) * (H_ * 2) + k0 * 2 + kb;
      const char* srcB = (const char*)wout  + (size_t)(n0 + rr) * (H_ * 2) + k0 * 2 + kb;
      char* dstA = (char*)As + (size_t)(rnd * 256 + w * 64) * 16;
      char* dstB = (char*)Bs + (size_t)(rnd * 256 + w * 64) * 16;
      __builtin_amdgcn_global_load_lds((const __attribute__((address_space(1))) void*)srcA,
                                       (__attribute__((address_space(3))) void*)dstA, 16, 0, 0);
      __builtin_amdgcn_global_load_lds((const __attribute__((address_space(1))) void*)srcB,
                                       (__attribute__((address_space(3))) void*)dstB, 16, 0, 0);
    }
    __syncthreads();
#pragma unroll
    for (int kk = 0; kk < 2; ++kk) {
      f16x8 bq[4];
#pragma unroll
      for (int ct = 0; ct < 4; ++ct) {
        int coll = wc * 64 + ct * 16 + lr;
        bq[ct] = *(const f16x8*)((const char*)Bs + coll * 128 +
                                 ((kk * 64 + lg * 16) ^ ((coll & 7) << 4)));
      }
#pragma unroll
      for (int rt = 0; rt < 4; ++rt) {
        int rowl = wr * 64 + rt * 16 + lr;
        f16x8 afr = *(const f16x8*)((const char*)As + rowl * 128 +
                                    ((kk * 64 + lg * 16) ^ ((rowl & 7) << 4)));
#pragma unroll
        for (int ct = 0; ct < 4; ++ct)
          acc[rt][ct] = __builtin_amdgcn_mfma_f32_16x16x32_f16(afr, bq[ct], acc[rt][ct], 0, 0, 0);
      }
    }
    __syncthreads();
  }
  // epilogue: bias + LeakyReLU, scatter to [b][t][o]
#pragma unroll
  for (int rt = 0; rt < 4; ++rt)
#pragma unroll
    for (int ct = 0; ct < 4; ++ct) {
      int n = n0 + wc * 64 + ct * 16 + lr;
      float bo = bout[n];
#pragma unroll
      for (int reg = 0; reg < 4; ++reg) {
        int rg = m0 + wr * 64 + rt * 16 + lg * 4 + reg;   // flat row = t*128 + b
        float v = acc[rt][ct][reg] + bo;
        v = v >= 0.f ? v : 0.2f * v;
        out[(size_t)(rg & 127) * (T_ * O_) + (size_t)(rg >> 7) * O_ + n] = v;
      }
    }
}

// ---------------- launch --------------------------------------------------------------
extern "C" void kernel_launch(void* const* d_in, const int* in_sizes, int n_in,
                              void* d_out, int out_size, void* d_ws, size_t ws_size,
                              hipStream_t stream) {
  const float* z    = (const float*)d_in[0];
  const float* Wfch = (const float*)d_in[2];
  const float* bfch = (const float*)d_in[3];
  const float* Wfcc = (const float*)d_in[4];
  const float* bfcc = (const float*)d_in[5];
  const float* Wih  = (const float*)d_in[6];
  const float* bih  = (const float*)d_in[7];
  const float* Whh  = (const float*)d_in[8];
  const float* bhh  = (const float*)d_in[9];
  const float* x0   = (const float*)d_in[10];
  const float* Wout = (const float*)d_in[11];
  const float* bout = (const float*)d_in[12];
  float* out = (float*)d_out;

  if (ws_size < WS_NEED) return;

  char* ws = (char*)d_ws;
  f16* hs      = (f16*)(ws + OFF_HS);
  float* c0    = (float*)(ws + OFF_C0);
  float* biasc = (float*)(ws + OFF_BIASC);
  float* vec0  = (float*)(ws + OFF_VEC0);
  f16* wouth   = (f16*)(ws + OFF_WOUT);
  f16* zh      = (f16*)(ws + OFF_ZH);
  unsigned int* bar = (unsigned int*)(ws + OFF_BAR);

  hipLaunchKernelGGL(k_misc, dim3(256), dim3(256), 0, stream, z, Wout, zh, wouth, bar);
  hipLaunchKernelGGL(k_init, dim3(64), dim3(256), 0, stream, zh, Wfch, Wfcc, bfch, bfcc, hs, c0);
  hipLaunchKernelGGL(k_bias, dim3(16), dim3(256), 0, stream, Wih, bih, bhh, x0, biasc, vec0);
  hipLaunchKernelGGL(k_lstm, dim3(256), dim3(256), 0, stream, Wih, Whh, hs, c0, biasc, vec0, bar);
  hipLaunchKernelGGL(k_proj, dim3(2048), dim3(256), 0, stream, hs, wouth, bout, out);
}

// Round 4
// 2431.883 us; speedup vs baseline: 4.6173x; 1.1540x over previous
//
#include <hip/hip_runtime.h>
#include <hip/hip_fp16.h>

#define B_    128
#define DIN_  512
#define H_    1024
#define T_    256
#define O_    1024

typedef _Float16 f16;
typedef _Float16 f16x8 __attribute__((ext_vector_type(8)));
typedef float    f32x4 __attribute__((ext_vector_type(4)));
typedef unsigned long long u64;

// workspace layout (bytes)
#define OFF_HS    0ull                 // (T_+1)*B_*H_ f16 (slot t = h_t; slot 0 = h0)
#define OFF_C0    67371008ull          // B_*H_ f32
#define OFF_BIASC 67895296ull          // 4096 f32 (rearranged b_ih+b_hh)
#define OFF_VEC0  67911680ull          // 4096 f32 (rearranged x0@W_ih^T + b_ih + b_hh)
#define OFF_ZH    67928064ull          // B_*DIN_ f16
#define WS_NEED   68059136ull

__device__ __forceinline__ float sigm_f(float x) {
  return 1.f / (1.f + __expf(-x));
}
__device__ __forceinline__ float tanh_f(float x) {
  float ax = fabsf(x);
  float e = __expf(-2.f * ax);
  float t = (1.f - e) / (1.f + e);
  return x < 0.f ? -t : t;
}

// ---------------- K0: convert z to fp16; poison hs slots 1..T with f16-NaN ------------
// h = sigmoid*tanh can never be 0xFFFF (NaN), so all-ones marks "not yet written".
__global__ void k_misc(const float* __restrict__ z, f16* __restrict__ zh,
                       uint4* __restrict__ pois) {
  int tid = blockIdx.x * blockDim.x + threadIdx.x;
  int nt  = gridDim.x * blockDim.x;
  for (int i = tid; i < B_ * DIN_; i += nt) zh[i] = (f16)z[i];
  uint4 pv = make_uint4(~0u, ~0u, ~0u, ~0u);
  const int np = T_ * B_ * H_ / 8;      // uint4 = 8 f16
  for (int i = tid; i < np; i += nt) pois[i] = pv;
}

// ---------------- K2: bias vectors (rearranged per block layout) ----------------------
// idx = cn*64 + jj*4 + gate, where n = gate*H_ + cn*16 + jj
__global__ void k_bias(const float* __restrict__ Wih, const float* __restrict__ bih,
                       const float* __restrict__ bhh, const float* __restrict__ x0,
                       float* __restrict__ biasc, float* __restrict__ vec0) {
  __shared__ float xs[H_];
  for (int i = threadIdx.x; i < H_; i += blockDim.x) xs[i] = x0[i];
  __syncthreads();
  int n = blockIdx.x * blockDim.x + threadIdx.x;   // 0..4095
  const float* wr = Wih + (size_t)n * H_;
  float s = 0.f;
  for (int k = 0; k < H_; k += 4) {
    float4 w4 = *(const float4*)(wr + k);
    s += w4.x * xs[k] + w4.y * xs[k + 1] + w4.z * xs[k + 2] + w4.w * xs[k + 3];
  }
  float bc = bih[n] + bhh[n];
  int g = n >> 10, hc = n & (H_ - 1);
  int cn = hc >> 4, jj = hc & 15;
  int idx = cn * 64 + jj * 4 + g;
  biasc[idx] = bc;
  vec0[idx]  = s + bc;
}

// ---------------- K1: h0 / c0 via fp16 MFMA ([128,512] x [512,2048]) ------------------
__global__ __launch_bounds__(256) void k_init(
    const f16* __restrict__ zh, const float* __restrict__ Wh, const float* __restrict__ Wc,
    const float* __restrict__ bh, const float* __restrict__ bc,
    f16* __restrict__ hs0, float* __restrict__ c0) {
  __shared__ float red[4 * 128 * 32];   // 64 KB
  int tid = threadIdx.x, l = tid & 63, w = tid >> 6;
  int lr = l & 15, lg = l >> 4;
  int n0 = blockIdx.x * 32;             // 64 blocks x 32 cols of 2048
  int ks = w * 128;                     // K-split per wave
  f32x4 acc[8][2];
#pragma unroll
  for (int rt = 0; rt < 8; ++rt)
#pragma unroll
    for (int ct = 0; ct < 2; ++ct) acc[rt][ct] = (f32x4){0.f, 0.f, 0.f, 0.f};

#pragma unroll
  for (int kt = 0; kt < 4; ++kt) {
    int k0 = ks + kt * 32 + lg * 8;
    f16x8 bf[2];
#pragma unroll
    for (int ct = 0; ct < 2; ++ct) {
      int n = n0 + ct * 16 + lr;
      const float* src = (n < H_) ? (Wh + (size_t)n * DIN_) : (Wc + (size_t)(n - H_) * DIN_);
      float4 a4 = *(const float4*)(src + k0);
      float4 b4 = *(const float4*)(src + k0 + 4);
      bf[ct] = (f16x8){(f16)a4.x, (f16)a4.y, (f16)a4.z, (f16)a4.w,
                       (f16)b4.x, (f16)b4.y, (f16)b4.z, (f16)b4.w};
    }
#pragma unroll
    for (int rt = 0; rt < 8; ++rt) {
      f16x8 af = *(const f16x8*)(zh + (size_t)(rt * 16 + lr) * DIN_ + k0);
#pragma unroll
      for (int ct = 0; ct < 2; ++ct)
        acc[rt][ct] = __builtin_amdgcn_mfma_f32_16x16x32_f16(af, bf[ct], acc[rt][ct], 0, 0, 0);
    }
  }
#pragma unroll
  for (int rt = 0; rt < 8; ++rt)
#pragma unroll
    for (int ct = 0; ct < 2; ++ct) {
      int c = ct * 16 + lr;
#pragma unroll
      for (int reg = 0; reg < 4; ++reg) {
        int rowloc = rt * 16 + lg * 4 + reg;
        red[(w * 128 + rowloc) * 32 + c] = acc[rt][ct][reg];
      }
    }
  __syncthreads();
  for (int i = 0; i < 16; ++i) {
    int e = i * 256 + tid;              // 4096 outputs
    int row = e & 127, c = e >> 7;
    float s = 0.f;
#pragma unroll
    for (int ww = 0; ww < 4; ++ww) s += red[(ww * 128 + row) * 32 + c];
    int n = n0 + c;
    if (n < H_) { s += bh[n]; hs0[(size_t)row * H_ + n] = (f16)s; }
    else        { s += bc[n - H_]; c0[(size_t)row * H_ + (n - H_)] = s; }
  }
}

// ---------------- persistent LSTM kernel (recurrence + fused projection) --------------
// 256 blocks x 256 thr. 4 groups x 64 blocks; group owns 32 batch rows.
// block: 32 rows x 16 h-cols (64 gate-cols, 16 out-cols). 4 waves K-split (256 each).
// Cross-block transport: relaxed agent atomics; readiness signaled by the DATA itself
// (poison = f16 NaN 0xFFFF, impossible as a real h value). No fences, no flags.
__device__ __forceinline__ void load_bf(f16x8 (&bf)[4][8], const float* __restrict__ Wih,
                                        const float* __restrict__ Whh, bool comb,
                                        int hc0, int tid) {
  int l = tid & 63, w = tid >> 6, lr = l & 15, lg = l >> 4;
  int ks = w * 256;
#pragma unroll
  for (int ct = 0; ct < 4; ++ct) {
    int c = ct * 16 + lr;
    int gate = c & 3, jj = c >> 2;
    size_t nrow = (size_t)(gate * H_ + hc0 + jj) * H_;
#pragma unroll
    for (int kt = 0; kt < 8; ++kt) {
      int k0 = ks + kt * 32 + lg * 8;
      float4 h0v = *(const float4*)(Whh + nrow + k0);
      float4 h1v = *(const float4*)(Whh + nrow + k0 + 4);
      if (comb) {
        float4 i0 = *(const float4*)(Wih + nrow + k0);
        float4 i1 = *(const float4*)(Wih + nrow + k0 + 4);
        h0v.x += i0.x; h0v.y += i0.y; h0v.z += i0.z; h0v.w += i0.w;
        h1v.x += i1.x; h1v.y += i1.y; h1v.z += i1.z; h1v.w += i1.w;
      }
      bf[ct][kt] = (f16x8){(f16)h0v.x, (f16)h0v.y, (f16)h0v.z, (f16)h0v.w,
                           (f16)h1v.x, (f16)h1v.y, (f16)h1v.z, (f16)h1v.w};
    }
  }
}

// poll-load the wave's A slice: re-load until no 8B granule is all-ones
__device__ __forceinline__ void poll_load_af(f16x8 (&af)[2][8], const f16* __restrict__ hsrc,
                                             int rbase, int ks, int lr, int lg) {
  int guard = 0;
  while (true) {
    int clean = 1;
#pragma unroll
    for (int rt = 0; rt < 2; ++rt)
#pragma unroll
      for (int kt = 0; kt < 8; ++kt) {
        const u64* p = (const u64*)(hsrc + (size_t)(rbase + rt * 16 + lr) * H_ +
                                    (ks + kt * 32 + lg * 8));
        union { u64 q[2]; f16x8 v; } tm;
        tm.q[0] = __hip_atomic_load(p,     __ATOMIC_RELAXED, __HIP_MEMORY_SCOPE_AGENT);
        tm.q[1] = __hip_atomic_load(p + 1, __ATOMIC_RELAXED, __HIP_MEMORY_SCOPE_AGENT);
        clean &= (int)(tm.q[0] != ~0ull) & (int)(tm.q[1] != ~0ull);
        af[rt][kt] = tm.v;
      }
    if (__all(clean)) break;
    if (++guard > 4096) break;          // broken sync -> wrong answer, never a hang
    if (guard > 2) __builtin_amdgcn_s_sleep(1);
  }
}

__device__ __forceinline__ void lstm_step(
    int t, f16* __restrict__ hs, const f16x8 (&bf)[4][8], const f16x8 (&bfo)[8],
    const float* __restrict__ bias_s, const float* __restrict__ bout_s,
    float* __restrict__ red, float* __restrict__ red2, float* __restrict__ cst,
    f16* __restrict__ hlds, float* __restrict__ out,
    int tid, int rbase, int hc0) {
  int l = tid & 63, w = tid >> 6, lr = l & 15, lg = l >> 4;
  int ks = w * 256;
  const f16* hsrc = hs + (size_t)t * (B_ * H_);
  f16* hdst = hs + (size_t)(t + 1) * (B_ * H_);
  const bool doproj = (t > 0);          // af = h_t -> out time t-1

  f16x8 af[2][8];
  poll_load_af(af, hsrc, rbase, ks, lr, lg);

  f32x4 acc[2][4];
  f32x4 acco[2];
#pragma unroll
  for (int rt = 0; rt < 2; ++rt) {
    acco[rt] = (f32x4){0.f, 0.f, 0.f, 0.f};
#pragma unroll
    for (int ct = 0; ct < 4; ++ct) acc[rt][ct] = (f32x4){0.f, 0.f, 0.f, 0.f};
  }
#pragma unroll
  for (int kt = 0; kt < 8; ++kt)
#pragma unroll
    for (int rt = 0; rt < 2; ++rt) {
#pragma unroll
      for (int ct = 0; ct < 4; ++ct)
        acc[rt][ct] = __builtin_amdgcn_mfma_f32_16x16x32_f16(af[rt][kt], bf[ct][kt],
                                                             acc[rt][ct], 0, 0, 0);
      if (doproj)
        acco[rt] = __builtin_amdgcn_mfma_f32_16x16x32_f16(af[rt][kt], bfo[kt],
                                                          acco[rt], 0, 0, 0);
    }
  __syncthreads();                       // red/red2 reuse guard
  // gate partials: [w][rowloc 32][c 64], bank-XOR on c bit4 by lg&1
#pragma unroll
  for (int rt = 0; rt < 2; ++rt)
#pragma unroll
    for (int ct = 0; ct < 4; ++ct) {
      int c = (ct * 16 + lr) ^ ((lg & 1) << 4);
#pragma unroll
      for (int reg = 0; reg < 4; ++reg) {
        int rowloc = rt * 16 + lg * 4 + reg;
        red[(w * 32 + rowloc) * 64 + c] = acc[rt][ct][reg];
      }
    }
  if (doproj) {
#pragma unroll
    for (int rt = 0; rt < 2; ++rt)
#pragma unroll
      for (int reg = 0; reg < 4; ++reg) {
        int rowloc = rt * 16 + lg * 4 + reg;
        red2[(w * 32 + rowloc) * 16 + lr] = acco[rt][reg];
      }
  }
  __syncthreads();
  // gate reduce + cell update -> hlds (critical path)
#pragma unroll
  for (int i = 0; i < 2; ++i) {
    int e = i * 256 + tid;
    int row = e >> 4, jj = e & 15;
    int xw = (row >> 2) & 1;
    float g0 = 0.f, g1 = 0.f, g2 = 0.f, g3 = 0.f;
#pragma unroll
    for (int ww = 0; ww < 4; ++ww) {
      f32x4 v = *(const f32x4*)(red + (size_t)((ww * 32 + row) * 64) + ((jj * 4) ^ (xw << 4)));
      g0 += v[0]; g1 += v[1]; g2 += v[2]; g3 += v[3];
    }
    float Gi = g0 + bias_s[jj * 4 + 0];
    float Gf = g1 + bias_s[jj * 4 + 1];
    float Gg = g2 + bias_s[jj * 4 + 2];
    float Go = g3 + bias_s[jj * 4 + 3];
    float ig = sigm_f(Gi), fg = sigm_f(Gf), gg = tanh_f(Gg), og = sigm_f(Go);
    float cold = cst[e];
    float cnew = fg * cold + ig * gg;
    cst[e] = cnew;
    float hnew = og * tanh_f(cnew);
    hlds[row * 16 + jj] = (f16)hnew;
  }
  __syncthreads();
  // wave 0: publish h (fire-and-forget; data IS the ready flag)
  if (tid < 64) {
    const u64* q = (const u64*)hlds;
#pragma unroll
    for (int r2 = 0; r2 < 2; ++r2) {
      int idx = r2 * 64 + tid;           // 0..127 = row(32) x qq(4)
      int row = idx >> 2, qq = idx & 3;
      u64 val = q[row * 4 + qq];
      u64* dst = (u64*)(hdst + (size_t)(rbase + row) * H_ + hc0) + qq;
      __hip_atomic_store(dst, val, __ATOMIC_RELAXED, __HIP_MEMORY_SCOPE_AGENT);
    }
  }
  // projection epilogue for out time t-1 (off critical path, overlaps MALL transit)
  if (doproj) {
    int tout = t - 1;
#pragma unroll
    for (int i = 0; i < 2; ++i) {
      int e = i * 256 + tid;
      int row = e >> 4, col = e & 15;
      float s = 0.f;
#pragma unroll
      for (int ww = 0; ww < 4; ++ww) s += red2[((ww * 32 + row) << 4) + col];
      float v = s + bout_s[col];
      v = v >= 0.f ? v : 0.2f * v;
      out[(size_t)(rbase + row) * (T_ * O_) + (size_t)tout * O_ + hc0 + col] = v;
    }
  }
}

__global__ __launch_bounds__(256, 1) void k_lstm(
    const float* __restrict__ Wih, const float* __restrict__ Whh,
    const float* __restrict__ Wout, const float* __restrict__ bout,
    f16* __restrict__ hs, const float* __restrict__ c0,
    const float* __restrict__ biasc, const float* __restrict__ vec0,
    float* __restrict__ out) {
  __shared__ float red[4 * 32 * 64];     // 32 KB gate partials
  __shared__ float red2[4 * 32 * 16];    // 8 KB proj partials
  __shared__ float cst[512];             // cell state
  __shared__ f16 hlds[512];              // packed h tile
  __shared__ float bias0_s[64], biasc_s[64], bout_s[16];
  int tid = threadIdx.x;
  int bid = blockIdx.x;
  int grp = bid >> 6, cn = bid & 63;
  int rbase = grp * 32, hc0 = cn * 16;
  int l = tid & 63, w = tid >> 6, lr = l & 15, lg = l >> 4;
  int ks = w * 256;
  if (tid < 64) {
    bias0_s[tid] = vec0[cn * 64 + tid];
    biasc_s[tid] = biasc[cn * 64 + tid];
  }
  if (tid < 16) bout_s[tid] = bout[hc0 + tid];
  for (int i = tid; i < 512; i += 256) {
    int row = i >> 4, jj = i & 15;
    cst[i] = c0[(size_t)(rbase + row) * H_ + hc0 + jj];
  }
  __syncthreads();
  // projection B-frags: out-col = hc0 + lr, K rows = wave's slice
  f16x8 bfo[8];
  {
    const float* wr = Wout + (size_t)(hc0 + lr) * H_;
#pragma unroll
    for (int kt = 0; kt < 8; ++kt) {
      int k0 = ks + kt * 32 + lg * 8;
      float4 a4 = *(const float4*)(wr + k0);
      float4 b4 = *(const float4*)(wr + k0 + 4);
      bfo[kt] = (f16x8){(f16)a4.x, (f16)a4.y, (f16)a4.z, (f16)a4.w,
                        (f16)b4.x, (f16)b4.y, (f16)b4.z, (f16)b4.w};
    }
  }
  f16x8 bf[4][8];
  load_bf(bf, Wih, Whh, false, hc0, tid); // step 0: W_hh only
  lstm_step(0, hs, bf, bfo, bias0_s, bout_s, red, red2, cst, hlds, out, tid, rbase, hc0);
  load_bf(bf, Wih, Whh, true, hc0, tid);  // steps 1..: W_ih + W_hh
  for (int t = 1; t < T_; ++t)
    lstm_step(t, hs, bf, bfo, biasc_s, bout_s, red, red2, cst, hlds, out, tid, rbase, hc0);

  // epilogue: projection of slot T_ -> out time T_-1
  {
    const f16* hsrc = hs + (size_t)T_ * (B_ * H_);
    f16x8 af[2][8];
    poll_load_af(af, hsrc, rbase, ks, lr, lg);
    f32x4 acco[2];
#pragma unroll
    for (int rt = 0; rt < 2; ++rt) acco[rt] = (f32x4){0.f, 0.f, 0.f, 0.f};
#pragma unroll
    for (int kt = 0; kt < 8; ++kt)
#pragma unroll
      for (int rt = 0; rt < 2; ++rt)
        acco[rt] = __builtin_amdgcn_mfma_f32_16x16x32_f16(af[rt][kt], bfo[kt],
                                                          acco[rt], 0, 0, 0);
    __syncthreads();                     // guard red2 vs step T_-1 reads
#pragma unroll
    for (int rt = 0; rt < 2; ++rt)
#pragma unroll
      for (int reg = 0; reg < 4; ++reg) {
        int rowloc = rt * 16 + lg * 4 + reg;
        red2[(w * 32 + rowloc) * 16 + lr] = acco[rt][reg];
      }
    __syncthreads();
#pragma unroll
    for (int i = 0; i < 2; ++i) {
      int e = i * 256 + tid;
      int row = e >> 4, col = e & 15;
      float s = 0.f;
#pragma unroll
      for (int ww = 0; ww < 4; ++ww) s += red2[((ww * 32 + row) << 4) + col];
      float v = s + bout_s[col];
      v = v >= 0.f ? v : 0.2f * v;
      out[(size_t)(rbase + row) * (T_ * O_) + (size_t)(T_ - 1) * O_ + hc0 + col] = v;
    }
  }
}

// ---------------- launch --------------------------------------------------------------
extern "C" void kernel_launch(void* const* d_in, const int* in_sizes, int n_in,
                              void* d_out, int out_size, void* d_ws, size_t ws_size,
                              hipStream_t stream) {
  const float* z    = (const float*)d_in[0];
  const float* Wfch = (const float*)d_in[2];
  const float* bfch = (const float*)d_in[3];
  const float* Wfcc = (const float*)d_in[4];
  const float* bfcc = (const float*)d_in[5];
  const float* Wih  = (const float*)d_in[6];
  const float* bih  = (const float*)d_in[7];
  const float* Whh  = (const float*)d_in[8];
  const float* bhh  = (const float*)d_in[9];
  const float* x0   = (const float*)d_in[10];
  const float* Wout = (const float*)d_in[11];
  const float* bout = (const float*)d_in[12];
  float* out = (float*)d_out;

  if (ws_size < WS_NEED) return;

  char* ws = (char*)d_ws;
  f16* hs      = (f16*)(ws + OFF_HS);
  float* c0    = (float*)(ws + OFF_C0);
  float* biasc = (float*)(ws + OFF_BIASC);
  float* vec0  = (float*)(ws + OFF_VEC0);
  f16* zh      = (f16*)(ws + OFF_ZH);
  uint4* pois  = (uint4*)(ws + OFF_HS + (size_t)B_ * H_ * 2);  // slots 1..T_

  hipLaunchKernelGGL(k_misc, dim3(256), dim3(256), 0, stream, z, zh, pois);
  hipLaunchKernelGGL(k_init, dim3(64), dim3(256), 0, stream, zh, Wfch, Wfcc, bfch, bfcc, hs, c0);
  hipLaunchKernelGGL(k_bias, dim3(16), dim3(256), 0, stream, Wih, bih, bhh, x0, biasc, vec0);
  hipLaunchKernelGGL(k_lstm, dim3(256), dim3(256), 0, stream,
                     Wih, Whh, Wout, bout, hs, c0, biasc, vec0, out);
}

// Round 5
// 1809.875 us; speedup vs baseline: 6.2041x; 1.3437x over previous
//
#include <hip/hip_runtime.h>
#include <hip/hip_fp16.h>

#define B_    128
#define DIN_  512
#define H_    1024
#define T_    256
#define O_    1024

typedef _Float16 f16;
typedef _Float16 f16x8 __attribute__((ext_vector_type(8)));
typedef float    f32x4 __attribute__((ext_vector_type(4)));
typedef unsigned long long u64;

// workspace layout (bytes)
#define OFF_HS    0ull                 // (T_+1)*B_*H_ f16 (slot t = h_t; slot 0 = h0)
#define OFF_C0    67371008ull          // B_*H_ f32
#define OFF_BIASC 67895296ull          // 4096 f32 (rearranged b_ih+b_hh)
#define OFF_VEC0  67911680ull          // 4096 f32 (rearranged x0@W_ih^T + b_ih + b_hh)
#define OFF_ZH    67928064ull          // B_*DIN_ f16
#define OFF_SENT  68059136ull          // T_*4*256 u32 sentinels = 1 MB
#define WS_NEED   69107712ull

__device__ __forceinline__ float sigm_f(float x) {
  return 1.f / (1.f + __expf(-x));
}
__device__ __forceinline__ float tanh_f(float x) {
  float ax = fabsf(x);
  float e = __expf(-2.f * ax);
  float t = (1.f - e) / (1.f + e);
  return x < 0.f ? -t : t;
}

// ---------------- K0: convert z to fp16; zero sentinels -------------------------------
__global__ void k_misc(const float* __restrict__ z, f16* __restrict__ zh,
                       unsigned int* __restrict__ sent) {
  int tid = blockIdx.x * blockDim.x + threadIdx.x;
  int nt  = gridDim.x * blockDim.x;
  for (int i = tid; i < B_ * DIN_; i += nt) zh[i] = (f16)z[i];
  for (int i = tid; i < T_ * 4 * 256; i += nt) sent[i] = 0u;
}

// ---------------- K2: bias vectors (rearranged per block layout) ----------------------
// idx = cn*64 + jj*4 + gate, where n = gate*H_ + cn*16 + jj
__global__ void k_bias(const float* __restrict__ Wih, const float* __restrict__ bih,
                       const float* __restrict__ bhh, const float* __restrict__ x0,
                       float* __restrict__ biasc, float* __restrict__ vec0) {
  __shared__ float xs[H_];
  for (int i = threadIdx.x; i < H_; i += blockDim.x) xs[i] = x0[i];
  __syncthreads();
  int n = blockIdx.x * blockDim.x + threadIdx.x;   // 0..4095
  const float* wr = Wih + (size_t)n * H_;
  float s = 0.f;
  for (int k = 0; k < H_; k += 4) {
    float4 w4 = *(const float4*)(wr + k);
    s += w4.x * xs[k] + w4.y * xs[k + 1] + w4.z * xs[k + 2] + w4.w * xs[k + 3];
  }
  float bc = bih[n] + bhh[n];
  int g = n >> 10, hc = n & (H_ - 1);
  int cn = hc >> 4, jj = hc & 15;
  int idx = cn * 64 + jj * 4 + g;
  biasc[idx] = bc;
  vec0[idx]  = s + bc;
}

// ---------------- K1: h0 / c0 via fp16 MFMA ([128,512] x [512,2048]) ------------------
__global__ __launch_bounds__(256) void k_init(
    const f16* __restrict__ zh, const float* __restrict__ Wh, const float* __restrict__ Wc,
    const float* __restrict__ bh, const float* __restrict__ bc,
    f16* __restrict__ hs0, float* __restrict__ c0) {
  __shared__ float red[4 * 128 * 32];   // 64 KB
  int tid = threadIdx.x, l = tid & 63, w = tid >> 6;
  int lr = l & 15, lg = l >> 4;
  int n0 = blockIdx.x * 32;             // 64 blocks x 32 cols of 2048
  int ks = w * 128;                     // K-split per wave
  f32x4 acc[8][2];
#pragma unroll
  for (int rt = 0; rt < 8; ++rt)
#pragma unroll
    for (int ct = 0; ct < 2; ++ct) acc[rt][ct] = (f32x4){0.f, 0.f, 0.f, 0.f};

#pragma unroll
  for (int kt = 0; kt < 4; ++kt) {
    int k0 = ks + kt * 32 + lg * 8;
    f16x8 bf[2];
#pragma unroll
    for (int ct = 0; ct < 2; ++ct) {
      int n = n0 + ct * 16 + lr;
      const float* src = (n < H_) ? (Wh + (size_t)n * DIN_) : (Wc + (size_t)(n - H_) * DIN_);
      float4 a4 = *(const float4*)(src + k0);
      float4 b4 = *(const float4*)(src + k0 + 4);
      bf[ct] = (f16x8){(f16)a4.x, (f16)a4.y, (f16)a4.z, (f16)a4.w,
                       (f16)b4.x, (f16)b4.y, (f16)b4.z, (f16)b4.w};
    }
#pragma unroll
    for (int rt = 0; rt < 8; ++rt) {
      f16x8 af = *(const f16x8*)(zh + (size_t)(rt * 16 + lr) * DIN_ + k0);
#pragma unroll
      for (int ct = 0; ct < 2; ++ct)
        acc[rt][ct] = __builtin_amdgcn_mfma_f32_16x16x32_f16(af, bf[ct], acc[rt][ct], 0, 0, 0);
    }
  }
#pragma unroll
  for (int rt = 0; rt < 8; ++rt)
#pragma unroll
    for (int ct = 0; ct < 2; ++ct) {
      int c = ct * 16 + lr;
#pragma unroll
      for (int reg = 0; reg < 4; ++reg) {
        int rowloc = rt * 16 + lg * 4 + reg;
        red[(w * 128 + rowloc) * 32 + c] = acc[rt][ct][reg];
      }
    }
  __syncthreads();
  for (int i = 0; i < 16; ++i) {
    int e = i * 256 + tid;              // 4096 outputs
    int row = e & 127, c = e >> 7;
    float s = 0.f;
#pragma unroll
    for (int ww = 0; ww < 4; ++ww) s += red[(ww * 128 + row) * 32 + c];
    int n = n0 + c;
    if (n < H_) { s += bh[n]; hs0[(size_t)row * H_ + n] = (f16)s; }
    else        { s += bc[n - H_]; c0[(size_t)row * H_ + (n - H_)] = s; }
  }
}

// ---------------- persistent LSTM kernel (recurrence + fused projection) --------------
// 256 blocks x 256 thr. 4 groups x 64 blocks; group owns 32 batch rows.
// block: 32 rows x 16 h-cols. 4 waves K-split (256 each); wave owns 8 rows in act phase.
// Transport: h via agent-scope stores (to MALL) + NORMAL cached pulls (L2-amplified
// broadcast; each hs line read once per launch per CU -> guaranteed cold miss -> fresh).
// Readiness: per-(block,wave) 4B sentinel stored after vmcnt(0) drain of the h stores.
__device__ __forceinline__ void load_bf(f16x8 (&bf)[4][8], const float* __restrict__ Wih,
                                        const float* __restrict__ Whh, bool comb,
                                        int hc0, int tid) {
  int l = tid & 63, w = tid >> 6, lr = l & 15, lg = l >> 4;
  int ks = w * 256;
#pragma unroll
  for (int ct = 0; ct < 4; ++ct) {
    int c = ct * 16 + lr;
    int gate = c & 3, jj = c >> 2;
    size_t nrow = (size_t)(gate * H_ + hc0 + jj) * H_;
#pragma unroll
    for (int kt = 0; kt < 8; ++kt) {
      int k0 = ks + kt * 32 + lg * 8;
      float4 h0v = *(const float4*)(Whh + nrow + k0);
      float4 h1v = *(const float4*)(Whh + nrow + k0 + 4);
      if (comb) {
        float4 i0 = *(const float4*)(Wih + nrow + k0);
        float4 i1 = *(const float4*)(Wih + nrow + k0 + 4);
        h0v.x += i0.x; h0v.y += i0.y; h0v.z += i0.z; h0v.w += i0.w;
        h1v.x += i1.x; h1v.y += i1.y; h1v.z += i1.z; h1v.w += i1.w;
      }
      bf[ct][kt] = (f16x8){(f16)h0v.x, (f16)h0v.y, (f16)h0v.z, (f16)h0v.w,
                           (f16)h1v.x, (f16)h1v.y, (f16)h1v.z, (f16)h1v.w};
    }
  }
}

// poll the 64 sentinels covering this wave's K-slice (16 producer blocks x 4 waves)
__device__ __forceinline__ void poll_slice(const unsigned int* __restrict__ sent,
                                           int slotm1, int grp, int w, int l) {
  const unsigned int* sp = sent + ((size_t)slotm1 * 4 + grp) * 256 + w * 64 + l;
  int guard = 0;
  while (true) {
    unsigned v = __hip_atomic_load(sp, __ATOMIC_RELAXED, __HIP_MEMORY_SCOPE_AGENT);
    if (__all(v != 0)) break;
    if (++guard > 3000) break;          // broken sync -> wrong answer, never a hang
    __builtin_amdgcn_s_sleep(1);
  }
}

__device__ __forceinline__ void lstm_step(
    int t, f16* __restrict__ hs, const f16x8 (&bf)[4][8], const f16x8 (&bfo)[8],
    const float* __restrict__ bias_s, const float* __restrict__ bout_s,
    float* __restrict__ red, float* __restrict__ red2, float* __restrict__ cst,
    float* __restrict__ out, unsigned int* __restrict__ sent,
    int tid, int grp, int cn, int rbase, int hc0) {
  int l = tid & 63, w = tid >> 6, lr = l & 15, lg = l >> 4;
  int ks = w * 256;
  const f16* hsrc = hs + (size_t)t * (B_ * H_);
  f16* hdst = hs + (size_t)(t + 1) * (B_ * H_);
  const bool doproj = (t > 0);          // af = h_t -> out time t-1

  // 1) readiness (skip t=0: h0 comes from k_init via launch-boundary coherence)
  if (t > 0) poll_slice(sent, t - 1, grp, w, l);
  __builtin_amdgcn_sched_barrier(0);
  asm volatile("" ::: "memory");        // no hs load may be hoisted above the poll

  // 2) pull A: NORMAL cached loads (cold miss -> MALL -> L2/L1 fill, shared per XCD)
  f16x8 af[2][8];
#pragma unroll
  for (int rt = 0; rt < 2; ++rt)
#pragma unroll
    for (int kt = 0; kt < 8; ++kt)
      af[rt][kt] = *(const f16x8*)(hsrc + (size_t)(rbase + rt * 16 + lr) * H_ +
                                   (ks + kt * 32 + lg * 8));

  // 3) MFMA: gates + fused projection
  f32x4 acc[2][4];
  f32x4 acco[2];
#pragma unroll
  for (int rt = 0; rt < 2; ++rt) {
    acco[rt] = (f32x4){0.f, 0.f, 0.f, 0.f};
#pragma unroll
    for (int ct = 0; ct < 4; ++ct) acc[rt][ct] = (f32x4){0.f, 0.f, 0.f, 0.f};
  }
#pragma unroll
  for (int kt = 0; kt < 8; ++kt)
#pragma unroll
    for (int rt = 0; rt < 2; ++rt) {
#pragma unroll
      for (int ct = 0; ct < 4; ++ct)
        acc[rt][ct] = __builtin_amdgcn_mfma_f32_16x16x32_f16(af[rt][kt], bf[ct][kt],
                                                             acc[rt][ct], 0, 0, 0);
      if (doproj)
        acco[rt] = __builtin_amdgcn_mfma_f32_16x16x32_f16(af[rt][kt], bfo[kt],
                                                          acco[rt], 0, 0, 0);
    }

  // 4) partials to LDS
  __syncthreads();                      // guards prev-step reads of red/red2
#pragma unroll
  for (int rt = 0; rt < 2; ++rt)
#pragma unroll
    for (int ct = 0; ct < 4; ++ct) {
      int c = (ct * 16 + lr) ^ ((lg & 1) << 4);
#pragma unroll
      for (int reg = 0; reg < 4; ++reg) {
        int rowloc = rt * 16 + lg * 4 + reg;
        red[(w * 32 + rowloc) * 64 + c] = acc[rt][ct][reg];
      }
    }
  if (doproj) {
#pragma unroll
    for (int rt = 0; rt < 2; ++rt)
#pragma unroll
      for (int reg = 0; reg < 4; ++reg) {
        int rowloc = rt * 16 + lg * 4 + reg;
        red2[(w * 32 + rowloc) * 20 + lr] = acco[rt][reg];   // pitch 20: 2-way max
      }
  }
  __syncthreads();

  // 5) act phase: wave w owns local rows [w*8, w*8+8); 2 adjacent cols per lane
  {
    int row = w * 8 + (l >> 3);
    int c0 = (l & 7) * 2;
    int xw = (row >> 2) & 1;
    float hv[2];
#pragma unroll
    for (int cc = 0; cc < 2; ++cc) {
      int jj = c0 + cc;
      float g0 = 0.f, g1 = 0.f, g2 = 0.f, g3 = 0.f;
#pragma unroll
      for (int ww = 0; ww < 4; ++ww) {
        f32x4 v = *(const f32x4*)(red + (size_t)((ww * 32 + row) * 64) +
                                  ((jj * 4) ^ (xw << 4)));
        g0 += v[0]; g1 += v[1]; g2 += v[2]; g3 += v[3];
      }
      float Gi = g0 + bias_s[jj * 4 + 0];
      float Gf = g1 + bias_s[jj * 4 + 1];
      float Gg = g2 + bias_s[jj * 4 + 2];
      float Go = g3 + bias_s[jj * 4 + 3];
      float ig = sigm_f(Gi), fg = sigm_f(Gf), gg = tanh_f(Gg), og = sigm_f(Go);
      int e = row * 16 + jj;
      float cnew = fg * cst[e] + ig * gg;
      cst[e] = cnew;
      hv[cc] = og * tanh_f(cnew);
    }
    union { unsigned u; f16 h[2]; } pk;
    pk.h[0] = (f16)hv[0]; pk.h[1] = (f16)hv[1];
    __hip_atomic_store((unsigned int*)(hdst + (size_t)(rbase + row) * H_ + hc0 + c0),
                       pk.u, __ATOMIC_RELAXED, __HIP_MEMORY_SCOPE_AGENT);
  }
  // 6) drain h stores, then publish this wave's sentinel (data-before-flag)
  asm volatile("s_waitcnt vmcnt(0)" ::: "memory");
  if (l == 0)
    __hip_atomic_store(sent + ((size_t)t * 4 + grp) * 256 + cn * 4 + w, 1u,
                       __ATOMIC_RELAXED, __HIP_MEMORY_SCOPE_AGENT);

  // 7) out epilogue for time t-1 (off the critical path)
  if (doproj) {
    int tout = t - 1;
#pragma unroll
    for (int i = 0; i < 2; ++i) {
      int e = w * 128 + i * 64 + l;
      int rr = e >> 4, col = e & 15;
      float s = 0.f;
#pragma unroll
      for (int ww = 0; ww < 4; ++ww) s += red2[(ww * 32 + rr) * 20 + col];
      float vv = s + bout_s[col];
      vv = vv >= 0.f ? vv : 0.2f * vv;
      out[(size_t)(rbase + rr) * (T_ * O_) + (size_t)tout * O_ + hc0 + col] = vv;
    }
  }
}

__global__ __launch_bounds__(256, 1) void k_lstm(
    const float* __restrict__ Wih, const float* __restrict__ Whh,
    const float* __restrict__ Wout, const float* __restrict__ bout,
    f16* __restrict__ hs, const float* __restrict__ c0,
    const float* __restrict__ biasc, const float* __restrict__ vec0,
    unsigned int* __restrict__ sent, float* __restrict__ out) {
  __shared__ float red[4 * 32 * 64];     // 32 KB gate partials
  __shared__ float red2[4 * 32 * 20];    // 10 KB proj partials (pitch 20)
  __shared__ float cst[512];             // cell state
  __shared__ float bias0_s[64], biasc_s[64], bout_s[16];
  int tid = threadIdx.x;
  int bid = blockIdx.x;
  int grp = bid >> 6, cn = bid & 63;
  int rbase = grp * 32, hc0 = cn * 16;
  int l = tid & 63, w = tid >> 6, lr = l & 15, lg = l >> 4;
  int ks = w * 256;
  if (tid < 64) {
    bias0_s[tid] = vec0[cn * 64 + tid];
    biasc_s[tid] = biasc[cn * 64 + tid];
  }
  if (tid < 16) bout_s[tid] = bout[hc0 + tid];
  for (int i = tid; i < 512; i += 256) {
    int row = i >> 4, jj = i & 15;
    cst[i] = c0[(size_t)(rbase + row) * H_ + hc0 + jj];
  }
  __syncthreads();
  // projection B-frags: out-col = hc0 + lr, K rows = wave's slice
  f16x8 bfo[8];
  {
    const float* wr = Wout + (size_t)(hc0 + lr) * H_;
#pragma unroll
    for (int kt = 0; kt < 8; ++kt) {
      int k0 = ks + kt * 32 + lg * 8;
      float4 a4 = *(const float4*)(wr + k0);
      float4 b4 = *(const float4*)(wr + k0 + 4);
      bfo[kt] = (f16x8){(f16)a4.x, (f16)a4.y, (f16)a4.z, (f16)a4.w,
                        (f16)b4.x, (f16)b4.y, (f16)b4.z, (f16)b4.w};
    }
  }
  f16x8 bf[4][8];
  load_bf(bf, Wih, Whh, false, hc0, tid); // step 0: W_hh only
  lstm_step(0, hs, bf, bfo, bias0_s, bout_s, red, red2, cst, out, sent,
            tid, grp, cn, rbase, hc0);
  load_bf(bf, Wih, Whh, true, hc0, tid);  // steps 1..: W_ih + W_hh
  for (int t = 1; t < T_; ++t)
    lstm_step(t, hs, bf, bfo, biasc_s, bout_s, red, red2, cst, out, sent,
              tid, grp, cn, rbase, hc0);

  // epilogue: projection of slot T_ -> out time T_-1
  {
    poll_slice(sent, T_ - 1, grp, w, l);
    __builtin_amdgcn_sched_barrier(0);
    asm volatile("" ::: "memory");
    const f16* hsrc = hs + (size_t)T_ * (B_ * H_);
    f16x8 af[2][8];
#pragma unroll
    for (int rt = 0; rt < 2; ++rt)
#pragma unroll
      for (int kt = 0; kt < 8; ++kt)
        af[rt][kt] = *(const f16x8*)(hsrc + (size_t)(rbase + rt * 16 + lr) * H_ +
                                     (ks + kt * 32 + lg * 8));
    f32x4 acco[2];
#pragma unroll
    for (int rt = 0; rt < 2; ++rt) acco[rt] = (f32x4){0.f, 0.f, 0.f, 0.f};
#pragma unroll
    for (int kt = 0; kt < 8; ++kt)
#pragma unroll
      for (int rt = 0; rt < 2; ++rt)
        acco[rt] = __builtin_amdgcn_mfma_f32_16x16x32_f16(af[rt][kt], bfo[kt],
                                                          acco[rt], 0, 0, 0);
    __syncthreads();                     // guard red2 vs step T_-1 reads
#pragma unroll
    for (int rt = 0; rt < 2; ++rt)
#pragma unroll
      for (int reg = 0; reg < 4; ++reg) {
        int rowloc = rt * 16 + lg * 4 + reg;
        red2[(w * 32 + rowloc) * 20 + lr] = acco[rt][reg];
      }
    __syncthreads();
#pragma unroll
    for (int i = 0; i < 2; ++i) {
      int e = w * 128 + i * 64 + l;
      int rr = e >> 4, col = e & 15;
      float s = 0.f;
#pragma unroll
      for (int ww = 0; ww < 4; ++ww) s += red2[(ww * 32 + rr) * 20 + col];
      float vv = s + bout_s[col];
      vv = vv >= 0.f ? vv : 0.2f * vv;
      out[(size_t)(rbase + rr) * (T_ * O_) + (size_t)(T_ - 1) * O_ + hc0 + col] = vv;
    }
  }
}

// ---------------- launch --------------------------------------------------------------
extern "C" void kernel_launch(void* const* d_in, const int* in_sizes, int n_in,
                              void* d_out, int out_size, void* d_ws, size_t ws_size,
                              hipStream_t stream) {
  const float* z    = (const float*)d_in[0];
  const float* Wfch = (const float*)d_in[2];
  const float* bfch = (const float*)d_in[3];
  const float* Wfcc = (const float*)d_in[4];
  const float* bfcc = (const float*)d_in[5];
  const float* Wih  = (const float*)d_in[6];
  const float* bih  = (const float*)d_in[7];
  const float* Whh  = (const float*)d_in[8];
  const float* bhh  = (const float*)d_in[9];
  const float* x0   = (const float*)d_in[10];
  const float* Wout = (const float*)d_in[11];
  const float* bout = (const float*)d_in[12];
  float* out = (float*)d_out;

  if (ws_size < WS_NEED) return;

  char* ws = (char*)d_ws;
  f16* hs      = (f16*)(ws + OFF_HS);
  float* c0    = (float*)(ws + OFF_C0);
  float* biasc = (float*)(ws + OFF_BIASC);
  float* vec0  = (float*)(ws + OFF_VEC0);
  f16* zh      = (f16*)(ws + OFF_ZH);
  unsigned int* sent = (unsigned int*)(ws + OFF_SENT);

  hipLaunchKernelGGL(k_misc, dim3(256), dim3(256), 0, stream, z, zh, sent);
  hipLaunchKernelGGL(k_init, dim3(64), dim3(256), 0, stream, zh, Wfch, Wfcc, bfch, bfcc, hs, c0);
  hipLaunchKernelGGL(k_bias, dim3(16), dim3(256), 0, stream, Wih, bih, bhh, x0, biasc, vec0);
  hipLaunchKernelGGL(k_lstm, dim3(256), dim3(256), 0, stream,
                     Wih, Whh, Wout, bout, hs, c0, biasc, vec0, sent, out);
}

// Round 7
// 1404.503 us; speedup vs baseline: 7.9948x; 1.2886x over previous
//
#include <hip/hip_runtime.h>
#include <hip/hip_fp16.h>

#define B_    128
#define DIN_  512
#define H_    1024
#define T_    256
#define O_    1024

typedef _Float16 f16;
typedef _Float16 f16x8 __attribute__((ext_vector_type(8)));
typedef float    f32x4 __attribute__((ext_vector_type(4)));
typedef unsigned long long u64;

// workspace layout (bytes)
#define OFF_HS    0ull                 // (T_+1)*B_*H_ f16 (slot t = h_t; slot 0 = h0)
#define OFF_C0    67371008ull          // B_*H_ f32
#define OFF_BIASC 67895296ull          // 4096 f32 (rearranged b_ih+b_hh)
#define OFF_VEC0  67911680ull          // 4096 f32 (rearranged x0@W_ih^T + b_ih + b_hh)
#define OFF_ZH    67928064ull          // B_*DIN_ f16
#define OFF_SENT  68059136ull          // T_*4*256 u32 sentinels = 1 MB
#define WS_NEED   69107712ull

__device__ __forceinline__ float sigm_f(float x) {
  return 1.f / (1.f + __expf(-x));
}
__device__ __forceinline__ float tanh_f(float x) {
  float ax = fabsf(x);
  float e = __expf(-2.f * ax);
  float t = (1.f - e) / (1.f + e);
  return x < 0.f ? -t : t;
}

// ---------------- K0: convert z to fp16; zero sentinels -------------------------------
__global__ void k_misc(const float* __restrict__ z, f16* __restrict__ zh,
                       unsigned int* __restrict__ sent) {
  int tid = blockIdx.x * blockDim.x + threadIdx.x;
  int nt  = gridDim.x * blockDim.x;
  for (int i = tid; i < B_ * DIN_; i += nt) zh[i] = (f16)z[i];
  for (int i = tid; i < T_ * 4 * 256; i += nt) sent[i] = 0u;
}

// ---------------- K2: bias vectors (rearranged per block layout) ----------------------
// idx = cn*64 + jj*4 + gate, where n = gate*H_ + cn*16 + jj
__global__ void k_bias(const float* __restrict__ Wih, const float* __restrict__ bih,
                       const float* __restrict__ bhh, const float* __restrict__ x0,
                       float* __restrict__ biasc, float* __restrict__ vec0) {
  __shared__ float xs[H_];
  for (int i = threadIdx.x; i < H_; i += blockDim.x) xs[i] = x0[i];
  __syncthreads();
  int n = blockIdx.x * blockDim.x + threadIdx.x;   // 0..4095
  const float* wr = Wih + (size_t)n * H_;
  float s = 0.f;
  for (int k = 0; k < H_; k += 4) {
    float4 w4 = *(const float4*)(wr + k);
    s += w4.x * xs[k] + w4.y * xs[k + 1] + w4.z * xs[k + 2] + w4.w * xs[k + 3];
  }
  float bc = bih[n] + bhh[n];
  int g = n >> 10, hc = n & (H_ - 1);
  int cn = hc >> 4, jj = hc & 15;
  int idx = cn * 64 + jj * 4 + g;
  biasc[idx] = bc;
  vec0[idx]  = s + bc;
}

// ---------------- K1: h0 / c0 via fp16 MFMA ([128,512] x [512,2048]) ------------------
__global__ __launch_bounds__(256) void k_init(
    const f16* __restrict__ zh, const float* __restrict__ Wh, const float* __restrict__ Wc,
    const float* __restrict__ bh, const float* __restrict__ bc,
    f16* __restrict__ hs0, float* __restrict__ c0) {
  __shared__ float red[4 * 128 * 32];   // 64 KB
  int tid = threadIdx.x, l = tid & 63, w = tid >> 6;
  int lr = l & 15, lg = l >> 4;
  int n0 = blockIdx.x * 32;             // 64 blocks x 32 cols of 2048
  int ks = w * 128;                     // K-split per wave
  f32x4 acc[8][2];
#pragma unroll
  for (int rt = 0; rt < 8; ++rt)
#pragma unroll
    for (int ct = 0; ct < 2; ++ct) acc[rt][ct] = (f32x4){0.f, 0.f, 0.f, 0.f};

#pragma unroll
  for (int kt = 0; kt < 4; ++kt) {
    int k0 = ks + kt * 32 + lg * 8;
    f16x8 bf[2];
#pragma unroll
    for (int ct = 0; ct < 2; ++ct) {
      int n = n0 + ct * 16 + lr;
      const float* src = (n < H_) ? (Wh + (size_t)n * DIN_) : (Wc + (size_t)(n - H_) * DIN_);
      float4 a4 = *(const float4*)(src + k0);
      float4 b4 = *(const float4*)(src + k0 + 4);
      bf[ct] = (f16x8){(f16)a4.x, (f16)a4.y, (f16)a4.z, (f16)a4.w,
                       (f16)b4.x, (f16)b4.y, (f16)b4.z, (f16)b4.w};
    }
#pragma unroll
    for (int rt = 0; rt < 8; ++rt) {
      f16x8 af = *(const f16x8*)(zh + (size_t)(rt * 16 + lr) * DIN_ + k0);
#pragma unroll
      for (int ct = 0; ct < 2; ++ct)
        acc[rt][ct] = __builtin_amdgcn_mfma_f32_16x16x32_f16(af, bf[ct], acc[rt][ct], 0, 0, 0);
    }
  }
#pragma unroll
  for (int rt = 0; rt < 8; ++rt)
#pragma unroll
    for (int ct = 0; ct < 2; ++ct) {
      int c = ct * 16 + lr;
#pragma unroll
      for (int reg = 0; reg < 4; ++reg) {
        int rowloc = rt * 16 + lg * 4 + reg;
        red[(w * 128 + rowloc) * 32 + c] = acc[rt][ct][reg];
      }
    }
  __syncthreads();
  for (int i = 0; i < 16; ++i) {
    int e = i * 256 + tid;              // 4096 outputs
    int row = e & 127, c = e >> 7;
    float s = 0.f;
#pragma unroll
    for (int ww = 0; ww < 4; ++ww) s += red[(ww * 128 + row) * 32 + c];
    int n = n0 + c;
    if (n < H_) { s += bh[n]; hs0[(size_t)row * H_ + n] = (f16)s; }
    else        { s += bc[n - H_]; c0[(size_t)row * H_ + (n - H_)] = s; }
  }
}

// ---------------- persistent LSTM kernel (recurrence + fused projection) --------------
// 256 blocks x 256 thr. 4 groups x 64 blocks; group owns 32 batch rows.
// block: 32 rows x 16 h-cols. 4 waves K-split (256 each); wave owns 8 rows in act phase.
// Gate weights in registers (128 VGPR); PROJ WEIGHTS IN LDS (cuts reg pressure ~40).
// All projection work runs AFTER the sentinel publish -> hides MALL propagation.
__device__ __forceinline__ void load_bf(f16x8 (&bf)[4][8], const float* __restrict__ Wih,
                                        const float* __restrict__ Whh, bool comb,
                                        int hc0, int tid) {
  int l = tid & 63, w = tid >> 6, lr = l & 15, lg = l >> 4;
  int ks = w * 256;
#pragma unroll
  for (int ct = 0; ct < 4; ++ct) {
    int c = ct * 16 + lr;
    int gate = c & 3, jj = c >> 2;
    size_t nrow = (size_t)(gate * H_ + hc0 + jj) * H_;
#pragma unroll
    for (int kt = 0; kt < 8; ++kt) {
      int k0 = ks + kt * 32 + lg * 8;
      float4 h0v = *(const float4*)(Whh + nrow + k0);
      float4 h1v = *(const float4*)(Whh + nrow + k0 + 4);
      if (comb) {
        float4 i0 = *(const float4*)(Wih + nrow + k0);
        float4 i1 = *(const float4*)(Wih + nrow + k0 + 4);
        h0v.x += i0.x; h0v.y += i0.y; h0v.z += i0.z; h0v.w += i0.w;
        h1v.x += i1.x; h1v.y += i1.y; h1v.z += i1.z; h1v.w += i1.w;
      }
      bf[ct][kt] = (f16x8){(f16)h0v.x, (f16)h0v.y, (f16)h0v.z, (f16)h0v.w,
                           (f16)h1v.x, (f16)h1v.y, (f16)h1v.z, (f16)h1v.w};
    }
  }
}

// poll the 64 sentinels covering this wave's K-slice (16 producer blocks x 4 waves)
__device__ __forceinline__ void poll_slice(const unsigned int* __restrict__ sent,
                                           int slotm1, int grp, int w, int l) {
  const unsigned int* sp = sent + ((size_t)slotm1 * 4 + grp) * 256 + w * 64 + l;
  int guard = 0;
  while (true) {
    unsigned v = __hip_atomic_load(sp, __ATOMIC_RELAXED, __HIP_MEMORY_SCOPE_AGENT);
    if (__all(v != 0)) break;
    if (++guard > 3000) break;          // broken sync -> wrong answer, never a hang
    __builtin_amdgcn_s_sleep(1);
  }
}

__device__ __forceinline__ void lstm_step(
    int t, f16* __restrict__ hs, const f16x8 (&bf)[4][8],
    const float* __restrict__ bias_s, const float* __restrict__ bout_s,
    float* __restrict__ red, float* __restrict__ red2, float* __restrict__ cst,
    const char* __restrict__ wout_b, float* __restrict__ out,
    unsigned int* __restrict__ sent,
    int tid, int grp, int cn, int rbase, int hc0) {
  int l = tid & 63, w = tid >> 6, lr = l & 15, lg = l >> 4;
  int ks = w * 256;
  const f16* hsrc = hs + (size_t)t * (B_ * H_);
  f16* hdst = hs + (size_t)(t + 1) * (B_ * H_);
  const bool doproj = (t > 0);          // af = h_t -> out time t-1

  // 1) readiness (skip t=0: h0 comes from k_init via launch-boundary coherence)
  if (t > 0) poll_slice(sent, t - 1, grp, w, l);
  __builtin_amdgcn_sched_barrier(0);
  asm volatile("" ::: "memory");        // no hs load may be hoisted above the poll

  // 2) pull A: NORMAL cached loads (cold miss -> MALL -> L2/L1 fill, shared per XCD)
  f16x8 af[2][8];
#pragma unroll
  for (int rt = 0; rt < 2; ++rt)
#pragma unroll
    for (int kt = 0; kt < 8; ++kt)
      af[rt][kt] = *(const f16x8*)(hsrc + (size_t)(rbase + rt * 16 + lr) * H_ +
                                   (ks + kt * 32 + lg * 8));

  // 3) MFMA: gates only (proj deferred past publish)
  f32x4 acc[2][4];
#pragma unroll
  for (int rt = 0; rt < 2; ++rt)
#pragma unroll
    for (int ct = 0; ct < 4; ++ct) acc[rt][ct] = (f32x4){0.f, 0.f, 0.f, 0.f};
  __builtin_amdgcn_s_setprio(1);
#pragma unroll
  for (int kt = 0; kt < 8; ++kt)
#pragma unroll
    for (int rt = 0; rt < 2; ++rt)
#pragma unroll
      for (int ct = 0; ct < 4; ++ct)
        acc[rt][ct] = __builtin_amdgcn_mfma_f32_16x16x32_f16(af[rt][kt], bf[ct][kt],
                                                             acc[rt][ct], 0, 0, 0);
  __builtin_amdgcn_s_setprio(0);

  // 4) gate partials to LDS
  __syncthreads();                      // guards red vs prev act-reads, red2 vs prev reduce
#pragma unroll
  for (int rt = 0; rt < 2; ++rt)
#pragma unroll
    for (int ct = 0; ct < 4; ++ct) {
      int c = (ct * 16 + lr) ^ ((lg & 1) << 4);
#pragma unroll
      for (int reg = 0; reg < 4; ++reg) {
        int rowloc = rt * 16 + lg * 4 + reg;
        red[(w * 32 + rowloc) * 64 + c] = acc[rt][ct][reg];
      }
    }
  __syncthreads();

  // 5) act phase: wave w owns local rows [w*8, w*8+8); 2 adjacent cols per lane
  {
    int row = w * 8 + (l >> 3);
    int c0 = (l & 7) * 2;
    int xw = (row >> 2) & 1;
    float hv[2];
#pragma unroll
    for (int cc = 0; cc < 2; ++cc) {
      int jj = c0 + cc;
      float g0 = 0.f, g1 = 0.f, g2 = 0.f, g3 = 0.f;
#pragma unroll
      for (int ww = 0; ww < 4; ++ww) {
        f32x4 v = *(const f32x4*)(red + (size_t)((ww * 32 + row) * 64) +
                                  ((jj * 4) ^ (xw << 4)));
        g0 += v[0]; g1 += v[1]; g2 += v[2]; g3 += v[3];
      }
      float Gi = g0 + bias_s[jj * 4 + 0];
      float Gf = g1 + bias_s[jj * 4 + 1];
      float Gg = g2 + bias_s[jj * 4 + 2];
      float Go = g3 + bias_s[jj * 4 + 3];
      float ig = sigm_f(Gi), fg = sigm_f(Gf), gg = tanh_f(Gg), og = sigm_f(Go);
      int e = row * 16 + jj;
      float cnew = fg * cst[e] + ig * gg;
      cst[e] = cnew;
      hv[cc] = og * tanh_f(cnew);
    }
    union { unsigned u; f16 h[2]; } pk;
    pk.h[0] = (f16)hv[0]; pk.h[1] = (f16)hv[1];
    __hip_atomic_store((unsigned int*)(hdst + (size_t)(rbase + row) * H_ + hc0 + c0),
                       pk.u, __ATOMIC_RELAXED, __HIP_MEMORY_SCOPE_AGENT);
  }
  // 6) drain h stores, then publish this wave's sentinel (data-before-flag)
  asm volatile("s_waitcnt vmcnt(0)" ::: "memory");
  if (l == 0)
    __hip_atomic_store(sent + ((size_t)t * 4 + grp) * 256 + cn * 4 + w, 1u,
                       __ATOMIC_RELAXED, __HIP_MEMORY_SCOPE_AGENT);

  // 7) PROJECTION (fully post-publish: hides sentinel propagation to other XCDs)
  if (doproj) {
    f32x4 acco[2];
#pragma unroll
    for (int rt = 0; rt < 2; ++rt) acco[rt] = (f32x4){0.f, 0.f, 0.f, 0.f};
#pragma unroll
    for (int kt = 0; kt < 8; ++kt) {
      int byteoff = (lr * 2048 + (ks + kt * 32 + lg * 8) * 2) ^ ((lr & 7) << 4);
      f16x8 bq = *(const f16x8*)(wout_b + byteoff);
#pragma unroll
      for (int rt = 0; rt < 2; ++rt)
        acco[rt] = __builtin_amdgcn_mfma_f32_16x16x32_f16(af[rt][kt], bq, acco[rt], 0, 0, 0);
    }
#pragma unroll
    for (int rt = 0; rt < 2; ++rt)
#pragma unroll
      for (int reg = 0; reg < 4; ++reg) {
        int rowloc = rt * 16 + lg * 4 + reg;
        red2[(w * 32 + rowloc) * 20 + lr] = acco[rt][reg];   // pitch 20: 2-way max
      }
    __syncthreads();
    int tout = t - 1;
#pragma unroll
    for (int i = 0; i < 2; ++i) {
      int e = w * 128 + i * 64 + l;
      int rr = e >> 4, col = e & 15;
      float s = 0.f;
#pragma unroll
      for (int ww = 0; ww < 4; ++ww) s += red2[(ww * 32 + rr) * 20 + col];
      float vv = s + bout_s[col];
      vv = vv >= 0.f ? vv : 0.2f * vv;
      out[(size_t)(rbase + rr) * (T_ * O_) + (size_t)tout * O_ + hc0 + col] = vv;
    }
  }
}

__global__ __launch_bounds__(256, 1) void k_lstm(
    const float* __restrict__ Wih, const float* __restrict__ Whh,
    const float* __restrict__ Wout, const float* __restrict__ bout,
    f16* __restrict__ hs, const float* __restrict__ c0,
    const float* __restrict__ biasc, const float* __restrict__ vec0,
    unsigned int* __restrict__ sent, float* __restrict__ out) {
  __shared__ float red[4 * 32 * 64];     // 32 KB gate partials
  __shared__ float red2[4 * 32 * 20];    // 10 KB proj partials (pitch 20)
  __shared__ float cst[512];             // cell state
  __shared__ f16 wout_s[16 * 1024];      // 32 KB proj weights (XOR-swizzled)
  __shared__ float bias0_s[64], biasc_s[64], bout_s[16];
  int tid = threadIdx.x;
  int bid = blockIdx.x;
  int grp = bid >> 6, cn = bid & 63;
  int rbase = grp * 32, hc0 = cn * 16;
  int l = tid & 63, w = tid >> 6, lr = l & 15, lg = l >> 4;
  int ks = w * 256;
  char* wout_b = (char*)wout_s;
  if (tid < 64) {
    bias0_s[tid] = vec0[cn * 64 + tid];
    biasc_s[tid] = biasc[cn * 64 + tid];
  }
  if (tid < 16) bout_s[tid] = bout[hc0 + tid];
  for (int i = tid; i < 512; i += 256) {
    int row = i >> 4, jj = i & 15;
    cst[i] = c0[(size_t)(rbase + row) * H_ + hc0 + jj];
  }
  // stage Wout tile (16 out-cols x 1024 K) as f16 into LDS, XOR-swizzled
  for (int i = tid; i < 16 * 128; i += 256) {
    int col = i >> 7, g8 = i & 127;
    const float* src = Wout + (size_t)(hc0 + col) * H_ + g8 * 8;
    f16x8 v;
#pragma unroll
    for (int uu = 0; uu < 8; ++uu) v[uu] = (f16)src[uu];
    int byteoff = (col * 2048 + g8 * 16) ^ ((col & 7) << 4);
    *(f16x8*)(wout_b + byteoff) = v;
  }
  __syncthreads();

  f16x8 bf[4][8];
  load_bf(bf, Wih, Whh, false, hc0, tid); // step 0: W_hh only
  lstm_step(0, hs, bf, bias0_s, bout_s, red, red2, cst, wout_b, out, sent,
            tid, grp, cn, rbase, hc0);
  load_bf(bf, Wih, Whh, true, hc0, tid);  // steps 1..: W_ih + W_hh
  for (int t = 1; t < T_; ++t)
    lstm_step(t, hs, bf, biasc_s, bout_s, red, red2, cst, wout_b, out, sent,
              tid, grp, cn, rbase, hc0);

  // epilogue: projection of slot T_ -> out time T_-1
  {
    poll_slice(sent, T_ - 1, grp, w, l);
    __builtin_amdgcn_sched_barrier(0);
    asm volatile("" ::: "memory");
    const f16* hsrc = hs + (size_t)T_ * (B_ * H_);
    f16x8 af[2][8];
#pragma unroll
    for (int rt = 0; rt < 2; ++rt)
#pragma unroll
      for (int kt = 0; kt < 8; ++kt)
        af[rt][kt] = *(const f16x8*)(hsrc + (size_t)(rbase + rt * 16 + lr) * H_ +
                                     (ks + kt * 32 + lg * 8));
    f32x4 acco[2];
#pragma unroll
    for (int rt = 0; rt < 2; ++rt) acco[rt] = (f32x4){0.f, 0.f, 0.f, 0.f};
#pragma unroll
    for (int kt = 0; kt < 8; ++kt) {
      int byteoff = (lr * 2048 + (ks + kt * 32 + lg * 8) * 2) ^ ((lr & 7) << 4);
      f16x8 bq = *(const f16x8*)(wout_b + byteoff);
#pragma unroll
      for (int rt = 0; rt < 2; ++rt)
        acco[rt] = __builtin_amdgcn_mfma_f32_16x16x32_f16(af[rt][kt], bq, acco[rt], 0, 0, 0);
    }
    __syncthreads();                     // guard red2 vs step T_-1 reads
#pragma unroll
    for (int rt = 0; rt < 2; ++rt)
#pragma unroll
      for (int reg = 0; reg < 4; ++reg) {
        int rowloc = rt * 16 + lg * 4 + reg;
        red2[(w * 32 + rowloc) * 20 + lr] = acco[rt][reg];
      }
    __syncthreads();
#pragma unroll
    for (int i = 0; i < 2; ++i) {
      int e = w * 128 + i * 64 + l;
      int rr = e >> 4, col = e & 15;
      float s = 0.f;
#pragma unroll
      for (int ww = 0; ww < 4; ++ww) s += red2[(ww * 32 + rr) * 20 + col];
      float vv = s + bout_s[col];
      vv = vv >= 0.f ? vv : 0.2f * vv;
      out[(size_t)(rbase + rr) * (T_ * O_) + (size_t)(T_ - 1) * O_ + hc0 + col] = vv;
    }
  }
}

// ---------------- launch --------------------------------------------------------------
extern "C" void kernel_launch(void* const* d_in, const int* in_sizes, int n_in,
                              void* d_out, int out_size, void* d_ws, size_t ws_size,
                              hipStream_t stream) {
  const float* z    = (const float*)d_in[0];
  const float* Wfch = (const float*)d_in[2];
  const float* bfch = (const float*)d_in[3];
  const float* Wfcc = (const float*)d_in[4];
  const float* bfcc = (const float*)d_in[5];
  const float* Wih  = (const float*)d_in[6];
  const float* bih  = (const float*)d_in[7];
  const float* Whh  = (const float*)d_in[8];
  const float* bhh  = (const float*)d_in[9];
  const float* x0   = (const float*)d_in[10];
  const float* Wout = (const float*)d_in[11];
  const float* bout = (const float*)d_in[12];
  float* out = (float*)d_out;

  if (ws_size < WS_NEED) return;

  char* ws = (char*)d_ws;
  f16* hs      = (f16*)(ws + OFF_HS);
  float* c0    = (float*)(ws + OFF_C0);
  float* biasc = (float*)(ws + OFF_BIASC);
  float* vec0  = (float*)(ws + OFF_VEC0);
  f16* zh      = (f16*)(ws + OFF_ZH);
  unsigned int* sent = (unsigned int*)(ws + OFF_SENT);

  hipLaunchKernelGGL(k_misc, dim3(256), dim3(256), 0, stream, z, zh, sent);
  hipLaunchKernelGGL(k_init, dim3(64), dim3(256), 0, stream, zh, Wfch, Wfcc, bfch, bfcc, hs, c0);
  hipLaunchKernelGGL(k_bias, dim3(16), dim3(256), 0, stream, Wih, bih, bhh, x0, biasc, vec0);
  hipLaunchKernelGGL(k_lstm, dim3(256), dim3(256), 0, stream,
                     Wih, Whh, Wout, bout, hs, c0, biasc, vec0, sent, out);
}